// Round 14
// baseline (400.886 us; speedup 1.0000x reference)
//
#include <hip/hip_runtime.h>

#define DN  256   // DAGs
#define NN  1024  // nodes per DAG
#define PP  8     // max predecessors
#define LL  104   // feature dim
#define CLS 500   // classes
#define BT  512   // threads per block (8 waves)
#define TMAX 64   // node tile per level pass
#define KP  232   // padded K stride in bf16 elems
#define NG  26    // float4 feature groups (104/4)
#define OLP 108   // out_lds row pad (432B rows)
#define NEGBIG -3.0e38f

typedef __attribute__((ext_vector_type(8))) short short8;
typedef __attribute__((ext_vector_type(4))) short short4v;
typedef __attribute__((ext_vector_type(4))) float f32x4;

#define MFMA(a, b, c) __builtin_amdgcn_mfma_f32_16x16x32_bf16((a), (b), (c), 0, 0, 0)

// Raw barrier: LDS-visibility only; vmcnt NOT drained.
#define BAR_RAW() do {                                              \
    __builtin_amdgcn_sched_barrier(0);                              \
    asm volatile("s_waitcnt lgkmcnt(0)" ::: "memory");              \
    __builtin_amdgcn_s_barrier();                                   \
    __builtin_amdgcn_sched_barrier(0);                              \
} while (0)

__device__ __forceinline__ void split_bf16(float x, unsigned short& h, unsigned short& l) {
    unsigned u = __float_as_uint(x);
    h = (unsigned short)(u >> 16);
    float hf = __uint_as_float(u & 0xFFFF0000u);
    l = (unsigned short)(__float_as_uint(x - hf) >> 16);
}

__device__ __forceinline__ void split4(float4 v, short4v& h4, short4v& l4) {
    unsigned short h0,h1,h2,h3,l0,l1,l2,l3;
    split_bf16(v.x,h0,l0); split_bf16(v.y,h1,l1);
    split_bf16(v.z,h2,l2); split_bf16(v.w,h3,l3);
    h4 = (short4v){(short)h0,(short)h1,(short)h2,(short)h3};
    l4 = (short4v){(short)l0,(short)l1,(short)l2,(short)l3};
}

// masked exp-accumulate of one pred row (4 features), raw v_exp_f32.
// off -> arg = -3e38 -> exp2 = 0 exactly (v must be finite).
__device__ __forceinline__ void acc4(float4& num, float4& den, float4 aw, float4 v, bool on) {
    float e0 = __builtin_amdgcn_exp2f(on ? aw.x*v.x : NEGBIG);
    float e1 = __builtin_amdgcn_exp2f(on ? aw.y*v.y : NEGBIG);
    float e2 = __builtin_amdgcn_exp2f(on ? aw.z*v.z : NEGBIG);
    float e3 = __builtin_amdgcn_exp2f(on ? aw.w*v.w : NEGBIG);
    den.x += e0; den.y += e1; den.z += e2; den.w += e3;
    num.x = fmaf(e0, v.x, num.x);
    num.y = fmaf(e1, v.y, num.y);
    num.z = fmaf(e2, v.z, num.z);
    num.w = fmaf(e3, v.w, num.w);
}

// divide + split + x store for one task
__device__ __forceinline__ void store_x(int ni, int lg, float4 num, float4 den,
    short4v fth, short4v ftl, unsigned short (*xh)[KP], unsigned short (*xl)[KP])
{
    float4 agg = { __fdividef(num.x, den.x), __fdividef(num.y, den.y),
                   __fdividef(num.z, den.z), __fdividef(num.w, den.w) };
    short4v ah, al;
    split4(agg, ah, al);
    *(short4v*)&xh[ni][lg*4] = ah;
    *(short4v*)&xl[ni][lg*4] = al;
    *(short4v*)&xh[ni][LL + lg*4] = fth;
    *(short4v*)&xl[ni][LL + lg*4] = ftl;
}

// One block per DAG, 8 waves. Level-scheduled split-bf16 MFMA GEMM per level.
// Partial-softmax pipelining: old + prev-tile pred contributions are
// exp-accumulated during phase B (under MFMA shadow); round 1 of phase A only
// adds the fresh (just-written) preds, divides, and stores x.
__global__ __launch_bounds__(BT, 2) void dag_level_kernel(
    const float* __restrict__ atom,      // [DN][NN][LL]
    const int*   __restrict__ pred,      // [DN][NN][PP]
    const float* __restrict__ W_single,  // [LL][LL]
    const float* __restrict__ b_single,  // [LL]
    const float* __restrict__ W_merge,   // [LL][2*LL]
    const float* __restrict__ b_merge,   // [LL]
    const float* __restrict__ attn_w,    // [LL]
    float* __restrict__ out_all,         // ws: [DN][NN][LL]
    float* __restrict__ last_buf)        // ws: [DN][LL]
{
    __shared__ __align__(16) unsigned short x_hi[TMAX][KP];   // 29 KB
    __shared__ __align__(16) unsigned short x_lo[TMAX][KP];   // 29 KB
    __shared__ __align__(16) unsigned short ppos_lds[NN][PP]; // 16 KB pred positions
    __shared__ __align__(16) float out_lds[2][TMAX][OLP];     // 55 KB dbuf tile outputs
    __shared__ int   lvl[NN];                                 // 4 KB
    __shared__ int   cnt[NN];                                 // 4 KB
    __shared__ unsigned short order[NN];                      // 2 KB pos -> node
    __shared__ unsigned short pos_lds[NN];                    // 2 KB node -> pos
    __shared__ __align__(16) float s_attn2[LL];               // clamp(attn*log2e)
    __shared__ float s_bm[LL];
    __shared__ int   csum[64];
    __shared__ int   s_flag, s_maxlvl;

    const int d    = blockIdx.x;
    const int tid  = threadIdx.x;
    const int wid  = tid >> 6;
    const int lane = tid & 63;
    const int my_ni = tid / NG;
    const int my_lg = tid - my_ni * NG;

    const float* atom_d = atom + (size_t)d * NN * LL;
    const int*   pred_d = pred + (size_t)d * NN * PP;
    float*       out_d  = out_all + (size_t)d * NN * LL;

    // ---- W_merge fragments -> registers. Wave w owns nt = min(w,6) ----
    short8 wh[7], wl[7];
    {
        const int r = min(wid, 6)*16 + (lane & 15);
        #pragma unroll
        for (int kt = 0; kt < 7; ++kt) {
            const int k0 = kt*32 + (lane >> 4)*8;
            short8 hh, lo8;
            #pragma unroll
            for (int j = 0; j < 8; ++j) {
                float v = (r < LL && (k0 + j) < 2*LL) ? W_merge[r*2*LL + k0 + j] : 0.f;
                unsigned short a, b;
                split_bf16(v, a, b);
                hh[j] = (short)a; lo8[j] = (short)b;
            }
            wh[kt] = hh; wl[kt] = lo8;
        }
    }

    // ---- init ----
    for (int idx = tid; idx < TMAX * (KP - 2*LL); idx += BT) {
        int rr = idx / (KP - 2*LL), cc = 2*LL + (idx - rr*(KP - 2*LL));
        x_hi[rr][cc] = 0; x_lo[rr][cc] = 0;
    }
    if (tid < LL) {
        s_attn2[tid] = fmaxf(attn_w[tid] * 1.44269504f, 1e-30f);
        s_bm[tid] = b_merge[tid];
    }
    if (tid == 0) { s_flag = 0; s_maxlvl = 0; }
    lvl[tid] = 0; lvl[tid + BT] = 0;

    // ---- preds of my 2 nodes -> registers (global, coalesced) ----
    int mypA[PP], mypB[PP];
    {
        const int4* p4 = (const int4*)(pred_d + tid * PP);
        int4 a = p4[0], b = p4[1];
        mypA[0]=a.x; mypA[1]=a.y; mypA[2]=a.z; mypA[3]=a.w;
        mypA[4]=b.x; mypA[5]=b.y; mypA[6]=b.z; mypA[7]=b.w;
        const int4* q4 = (const int4*)(pred_d + (tid + BT) * PP);
        int4 c = q4[0], e = q4[1];
        mypB[0]=c.x; mypB[1]=c.y; mypB[2]=c.z; mypB[3]=c.w;
        mypB[4]=e.x; mypB[5]=e.y; mypB[6]=e.z; mypB[7]=e.w;
    }
    __syncthreads();

    // ---- 1. level relaxation: 2 nodes/thread, double monotone sweep ----
    for (int it = 1; it <= NN; ++it) {
        bool ch = false;
        #pragma unroll
        for (int rep = 0; rep < 2; ++rep) {
            int mxA = -1, mxB = -1;
            #pragma unroll
            for (int q = 0; q < PP; ++q) {
                if (mypA[q] >= 0) mxA = max(mxA, lvl[mypA[q]]);
                if (mypB[q] >= 0) mxB = max(mxB, lvl[mypB[q]]);
            }
            if (mxA + 1 != lvl[tid])      { lvl[tid]      = mxA + 1; ch = true; }
            if (mxB + 1 != lvl[tid + BT]) { lvl[tid + BT] = mxB + 1; ch = true; }
        }
        if (ch) s_flag = it;
        __syncthreads();
        int f = s_flag;
        __syncthreads();
        if (f != it) break;
    }
    atomicMax(&s_maxlvl, max(lvl[tid], lvl[tid + BT]));

    // ---- 2. counting sort by level (order + pos) ----
    cnt[tid] = 0; cnt[tid + BT] = 0;
    __syncthreads();
    atomicAdd(&cnt[lvl[tid]], 1);
    atomicAdd(&cnt[lvl[tid + BT]], 1);
    __syncthreads();
    if (tid < 64) { int s = 0; for (int i = 0; i < 16; ++i) s += cnt[tid*16 + i]; csum[tid] = s; }
    __syncthreads();
    if (tid == 0) { int run = 0; for (int t = 0; t < 64; ++t) { int c = csum[t]; csum[t] = run; run += c; } }
    __syncthreads();
    if (tid < 64) {
        int run = csum[tid];
        for (int i = 0; i < 16; ++i) { int c = cnt[tid*16 + i]; cnt[tid*16 + i] = run; run += c; }
    }
    __syncthreads();
    {
        int pos = atomicAdd(&cnt[lvl[tid]], 1);
        order[pos] = (unsigned short)tid;        pos_lds[tid] = (unsigned short)pos;
        pos = atomicAdd(&cnt[lvl[tid + BT]], 1);
        order[pos] = (unsigned short)(tid + BT); pos_lds[tid + BT] = (unsigned short)pos;
    }
    __syncthreads();

    // ---- 2b. position-space graph: ppos_lds[pos][q] (0xFFFF = none) ----
    {
        unsigned short tA[PP], tB[PP];
        #pragma unroll
        for (int q = 0; q < PP; ++q) {
            tA[q] = (mypA[q] < 0) ? (unsigned short)0xFFFFu : pos_lds[mypA[q]];
            tB[q] = (mypB[q] < 0) ? (unsigned short)0xFFFFu : pos_lds[mypB[q]];
        }
        int pA = pos_lds[tid], pB = pos_lds[tid + BT];
        *(short4v*)&ppos_lds[pA][0] = (short4v){(short)tA[0],(short)tA[1],(short)tA[2],(short)tA[3]};
        *(short4v*)&ppos_lds[pA][4] = (short4v){(short)tA[4],(short)tA[5],(short)tA[6],(short)tA[7]};
        *(short4v*)&ppos_lds[pB][0] = (short4v){(short)tB[0],(short)tB[1],(short)tB[2],(short)tB[3]};
        *(short4v*)&ppos_lds[pB][4] = (short4v){(short)tB[4],(short)tB[5],(short)tB[6],(short)tB[7]};
    }
    __syncthreads();

    const float4 my_aw = *(const float4*)&s_attn2[my_lg * 4];

    // ---- 3. level-0 (root) via W_single; write out_d + out_lds[1] ----
    {
        int nroots = cnt[0];
        for (int task = tid; task < nroots * LL; task += BT) {
            int ni = task / LL, r = task - ni * LL;
            int n = order[ni];
            float acc = b_single[r];
            const float* feat = atom_d + n * LL;
            const float* wr = W_single + r * LL;
            #pragma unroll 8
            for (int l = 0; l < LL; ++l) acc = fmaf(wr[l], feat[l], acc);
            float v = fmaxf(acc, 0.f);
            out_d[n * LL + r] = v;
            if (ni < TMAX) out_lds[1][ni][r] = v;
            if (n == NN - 1) last_buf[d * LL + r] = v;
        }
    }
    __syncthreads();

    const int maxlvl = s_maxlvl;

    // ---- prefetch/partial state for round-1 task (tid) of the NEXT tile ----
    float4  pf_num = {0,0,0,0}, pf_den = {0,0,0,0};  // partial softmax sums
    short4v pf_fth = {0,0,0,0}, pf_ftl = {0,0,0,0};  // pre-split feat
    short8  pf_pps = {0,0,0,0,0,0,0,0};

    int pt0 = 0, ptc = cnt[0];
    int wbuf = 0;

    // prologue: first tile of level 1 — all preds are level-0 = FRESH w.r.t.
    // pt0=0 (out_lds[1], handled in round 1); partials start at zero.
    if (maxlvl >= 1) {
        int s1 = cnt[0];
        int ntc0 = min(TMAX, cnt[1] - s1);
        if (tid < ntc0 * NG) {
            int n_ = order[s1 + my_ni];
            float4 ft = *(const float4*)&atom_d[n_ * LL + my_lg * 4];
            split4(ft, pf_fth, pf_ftl);
            pf_pps = *(const short8*)&ppos_lds[s1 + my_ni][0];
        }
    }

    // ---- 4. main level loop ----
    for (int L = 1; L <= maxlvl; ++L) {
        const int s = cnt[L - 1], e = cnt[L];
        for (int t0 = s; t0 < e; t0 += TMAX) {
            const int tc = min(TMAX, e - t0);
            const int ntask = tc * NG;
            const int pcopy = ptc * NG;
            const int rbuf = wbuf ^ 1;

            // ---------- phase A ----------
            // deferred global store of PREVIOUS tile (drained at A->B barrier)
            for (int ct = tid; ct < pcopy; ct += BT) {
                int ci = ct / NG, lg2 = ct - ci * NG;
                *(float4*)&out_d[(int)order[pt0 + ci] * LL + lg2 * 4] =
                    *(const float4*)&out_lds[rbuf][ci][lg2 * 4];
            }
            // round 1: add fresh preds (prev tile in rbuf) to partials, store
            if (tid < ntask) {
                float4 num = pf_num, den = pf_den;
                #pragma unroll
                for (int q = 0; q < PP; ++q) {
                    int pp = (unsigned short)pf_pps[q];
                    bool fresh = (pp >= pt0) && (pp < t0);
                    int slot = fresh ? (pp - pt0) : 0;
                    float4 lv = *(const float4*)&out_lds[rbuf][slot][my_lg * 4];
                    acc4(num, den, my_aw, lv, fresh);
                }
                store_x(my_ni, my_lg, num, den, pf_fth, pf_ftl, x_hi, x_lo);
            }
            // rounds 2+ (tc > 19 only): direct 2-way (old/prev; never fresh)
            for (int task = tid + BT; task < ntask; task += BT) {
                int ni = task / NG, lg = task - ni * NG;
                short8 pps = *(const short8*)&ppos_lds[t0 + ni][0];
                float4 aw4 = *(const float4*)&s_attn2[lg * 4];
                float4 gv2[PP];
                #pragma unroll
                for (int q = 0; q < PP; ++q) {
                    int pp = (unsigned short)pps[q];
                    bool old = pp < pt0;
                    int row = old ? (int)order[pp] : 0;
                    gv2[q] = *(const float4*)&out_d[row * LL + lg * 4];
                }
                float4 num = {0,0,0,0}, den = {0,0,0,0};
                #pragma unroll
                for (int q = 0; q < PP; ++q) {
                    int pp = (unsigned short)pps[q];
                    bool on   = pp < t0;            // valid (invalid = 0xFFFF)
                    bool prev = pp >= pt0;          // in rbuf
                    int slot = (prev && on) ? (pp - pt0) : 0;
                    float4 lv = *(const float4*)&out_lds[rbuf][slot][lg * 4];
                    float4 v;
                    v.x = prev ? lv.x : gv2[q].x; v.y = prev ? lv.y : gv2[q].y;
                    v.z = prev ? lv.z : gv2[q].z; v.w = prev ? lv.w : gv2[q].w;
                    acc4(num, den, aw4, v, on);
                }
                int n = order[t0 + ni];
                float4 ft = *(const float4*)&atom_d[n * LL + lg * 4];
                short4v fth, ftl;
                split4(ft, fth, ftl);
                store_x(ni, lg, num, den, fth, ftl, x_hi, x_lo);
            }
            __syncthreads();   // FULL: x visible; copy stores drained

            // ---------- phase B ----------
            int nt0 = 0, ntc = 0;
            if (t0 + TMAX < e)        { nt0 = t0 + TMAX; ntc = min(TMAX, e - nt0); }
            else if (L + 1 <= maxlvl) { nt0 = e;         ntc = min(TMAX, cnt[L + 1] - e); }
            const bool pf_act = tid < ntc * NG;

            // (1) issue loads for next tile: pps, atom feat, old-pred rows
            float4 gv[PP];
            float4 ft4 = {0.f, 0.f, 0.f, 0.f};
            if (pf_act) {
                int n_ = order[nt0 + my_ni];
                ft4 = *(const float4*)&atom_d[n_ * LL + my_lg * 4];
                pf_pps = *(const short8*)&ppos_lds[nt0 + my_ni][0];
                #pragma unroll
                for (int q = 0; q < PP; ++q) {
                    int pp = (unsigned short)pf_pps[q];
                    bool old = pp < pt0;
                    int row = old ? (int)order[pp] : 0;
                    gv[q] = *(const float4*)&out_d[row * LL + my_lg * 4];
                }
            }
            // (2) exp-accumulate PREV-tile preds (rbuf available now)
            pf_num = (float4){0,0,0,0}; pf_den = (float4){0,0,0,0};
            if (pf_act) {
                #pragma unroll
                for (int q = 0; q < PP; ++q) {
                    int pp = (unsigned short)pf_pps[q];
                    bool prev = (pp >= pt0) && (pp < t0);
                    int slot = prev ? (pp - pt0) : 0;
                    float4 lv = *(const float4*)&out_lds[rbuf][slot][my_lg * 4];
                    acc4(pf_num, pf_den, my_aw, lv, prev);
                }
            }

            // (3) MFMA: waves 0..6
            if (wid < 7) {
                const int mts = (tc + 15) >> 4;
                const int kg = (lane >> 4) * 8;
                const int r0 = wid*16 + (lane & 15);
                for (int mt = 0; mt < mts; ++mt) {
                    const int row_a = mt*16 + (lane & 15);
                    f32x4 a0 = {0.f,0.f,0.f,0.f}, b0 = {0.f,0.f,0.f,0.f}, c0 = {0.f,0.f,0.f,0.f};
                    #pragma unroll
                    for (int kt = 0; kt < 7; ++kt) {
                        const int k0 = kt*32 + kg;
                        short8 ah = *(const short8*)&x_hi[row_a][k0];
                        short8 al = *(const short8*)&x_lo[row_a][k0];
                        a0 = MFMA(ah, wh[kt], a0);
                        b0 = MFMA(ah, wl[kt], b0);
                        c0 = MFMA(al, wh[kt], c0);
                    }
                    f32x4 acc = a0 + b0 + c0;
                    if (r0 < LL) {
                        #pragma unroll
                        for (int j = 0; j < 4; ++j) {
                            int ni = mt*16 + (lane >> 4)*4 + j;
                            if (ni < tc) {
                                float v = fmaxf(acc[j] + s_bm[r0], 0.f);
                                out_lds[wbuf][ni][r0] = v;      // LDS only
                                int n = order[t0 + ni];
                                if (n == NN - 1) last_buf[d*LL + r0] = v;
                            }
                        }
                    }
                }
            }

            // (4) exp-accumulate OLD preds (loads landed under MFMA) + ft split
            if (pf_act) {
                #pragma unroll
                for (int q = 0; q < PP; ++q) {
                    int pp = (unsigned short)pf_pps[q];
                    bool old = pp < pt0;
                    acc4(pf_num, pf_den, my_aw, gv[q], old);
                }
                split4(ft4, pf_fth, pf_ftl);
            }

            BAR_RAW();   // lgkm-only: out_lds visible
            pt0 = t0; ptc = tc; wbuf ^= 1;
        }
    }
}

// Cross-DAG softmax pool + final classifier. Single block.
__global__ __launch_bounds__(256) void final_pool_kernel(
    const float* __restrict__ last_buf,  // [DN][LL]
    const float* __restrict__ dag_w,     // [LL]
    const float* __restrict__ W_final,   // [CLS][LL]
    const float* __restrict__ b_final,   // [CLS]
    float* __restrict__ out)             // [CLS]
{
    __shared__ float s_pooled[LL];
    const int tid = threadIdx.x;

    if (tid < LL) {
        float dw = dag_w[tid];
        float m = -1e30f;
        #pragma unroll 8
        for (int dd = 0; dd < DN; ++dd)
            m = fmaxf(m, dw * last_buf[dd * LL + tid]);
        float den = 0.f, num = 0.f;
        #pragma unroll 8
        for (int dd = 0; dd < DN; ++dd) {
            float v = last_buf[dd * LL + tid];
            float e = __expf(dw * v - m);
            den += e;
            num = fmaf(e, v, num);
        }
        s_pooled[tid] = num / den;
    }
    __syncthreads();

    for (int c = tid; c < CLS; c += 256) {
        float acc = b_final[c];
        const float* wr = W_final + c * LL;
        #pragma unroll 8
        for (int l = 0; l < LL; ++l) acc = fmaf(wr[l], s_pooled[l], acc);
        out[c] = acc;
    }
}

extern "C" void kernel_launch(void* const* d_in, const int* in_sizes, int n_in,
                              void* d_out, int out_size, void* d_ws, size_t ws_size,
                              hipStream_t stream) {
    const float* atom     = (const float*)d_in[0];
    const int*   pred     = (const int*)  d_in[1];
    const float* W_single = (const float*)d_in[2];
    const float* b_single = (const float*)d_in[3];
    const float* W_merge  = (const float*)d_in[4];
    const float* b_merge  = (const float*)d_in[5];
    const float* attn_w   = (const float*)d_in[6];
    const float* dag_w    = (const float*)d_in[7];
    const float* W_final  = (const float*)d_in[8];
    const float* b_final  = (const float*)d_in[9];
    float* out = (float*)d_out;

    float* out_all  = (float*)d_ws;                       // [DN][NN][LL]
    float* last_buf = out_all + (size_t)DN * NN * LL;     // [DN][LL]

    dag_level_kernel<<<DN, BT, 0, stream>>>(atom, pred, W_single, b_single,
                                            W_merge, b_merge, attn_w,
                                            out_all, last_buf);
    final_pool_kernel<<<1, 256, 0, stream>>>(last_buf, dag_w, W_final, b_final, out);
}

// Round 15
// 386.971 us; speedup vs baseline: 1.0360x; 1.0360x over previous
//
#include <hip/hip_runtime.h>

#define DN  256   // DAGs
#define NN  1024  // nodes per DAG
#define PP  8     // max predecessors
#define LL  104   // feature dim
#define CLS 500   // classes
#define BT  512   // threads per block (8 waves)
#define TMAX 64   // node tile per level pass
#define KP  232   // padded K stride in bf16 elems
#define NG2 52    // float2 feature groups per node (104/2)
#define NGC 26    // float4 groups (copy loop)
#define OLP 108   // out_lds row pad (432B rows)
#define NEGBIG -3.0e38f

typedef __attribute__((ext_vector_type(8))) short short8;
typedef __attribute__((ext_vector_type(4))) short short4v;
typedef __attribute__((ext_vector_type(4))) float f32x4;

#define MFMA(a, b, c) __builtin_amdgcn_mfma_f32_16x16x32_bf16((a), (b), (c), 0, 0, 0)

// Raw barrier: LDS-visibility only; vmcnt NOT drained.
#define BAR_RAW() do {                                              \
    __builtin_amdgcn_sched_barrier(0);                              \
    asm volatile("s_waitcnt lgkmcnt(0)" ::: "memory");              \
    __builtin_amdgcn_s_barrier();                                   \
    __builtin_amdgcn_sched_barrier(0);                              \
} while (0)

__device__ __forceinline__ void split_bf16(float x, unsigned short& h, unsigned short& l) {
    unsigned u = __float_as_uint(x);
    h = (unsigned short)(u >> 16);
    float hf = __uint_as_float(u & 0xFFFF0000u);
    l = (unsigned short)(__float_as_uint(x - hf) >> 16);
}

// exp-accumulate one pred row (2 features), raw v_exp_f32.
// v = NEGBIG encodes "skip" -> exp2 == 0 exactly (aw >= 1e-30).
__device__ __forceinline__ void acc2(float2& num, float2& den, float2 aw, float2 v) {
    float e0 = __builtin_amdgcn_exp2f(aw.x * v.x);
    float e1 = __builtin_amdgcn_exp2f(aw.y * v.y);
    den.x += e0; den.y += e1;
    num.x = fmaf(e0, v.x, num.x);
    num.y = fmaf(e1, v.y, num.y);
}
__device__ __forceinline__ void acc2m(float2& num, float2& den, float2 aw, float2 v, bool on) {
    float e0 = __builtin_amdgcn_exp2f(on ? aw.x * v.x : NEGBIG);
    float e1 = __builtin_amdgcn_exp2f(on ? aw.y * v.y : NEGBIG);
    den.x += e0; den.y += e1;
    num.x = fmaf(e0, v.x, num.x);
    num.y = fmaf(e1, v.y, num.y);
}

// divide + split + x store (2 features); ft arrives pre-split packed
__device__ __forceinline__ void store_x2(int ni, int lg, float2 num, float2 den,
    unsigned fth, unsigned ftl, unsigned short (*xh)[KP], unsigned short (*xl)[KP])
{
    float ax = __fdividef(num.x, den.x);
    float ay = __fdividef(num.y, den.y);
    unsigned short h0, l0, h1, l1;
    split_bf16(ax, h0, l0); split_bf16(ay, h1, l1);
    *(unsigned*)&xh[ni][lg*2] = (unsigned)h0 | ((unsigned)h1 << 16);
    *(unsigned*)&xl[ni][lg*2] = (unsigned)l0 | ((unsigned)l1 << 16);
    *(unsigned*)&xh[ni][LL + lg*2] = fth;
    *(unsigned*)&xl[ni][LL + lg*2] = ftl;
}

// One block per DAG, 8 waves. Level-scheduled split-bf16 MFMA GEMM per level.
// R12 structure (dbuf out_lds, deferred stores, raw B->A barrier) with finer
// (node, 2-feature) tasks so phase A spreads across all 8 waves; prefetch
// covers two rounds via two static register sets.
__global__ __launch_bounds__(BT, 2) void dag_level_kernel(
    const float* __restrict__ atom,      // [DN][NN][LL]
    const int*   __restrict__ pred,      // [DN][NN][PP]
    const float* __restrict__ W_single,  // [LL][LL]
    const float* __restrict__ b_single,  // [LL]
    const float* __restrict__ W_merge,   // [LL][2*LL]
    const float* __restrict__ b_merge,   // [LL]
    const float* __restrict__ attn_w,    // [LL]
    float* __restrict__ out_all,         // ws: [DN][NN][LL]
    float* __restrict__ last_buf)        // ws: [DN][LL]
{
    __shared__ __align__(16) unsigned short x_hi[TMAX][KP];   // 29 KB
    __shared__ __align__(16) unsigned short x_lo[TMAX][KP];   // 29 KB
    __shared__ __align__(16) unsigned short ppos_lds[NN][PP]; // 16 KB pred positions
    __shared__ __align__(16) float out_lds[2][TMAX][OLP];     // 55 KB dbuf tile outputs
    __shared__ int   lvl[NN];                                 // 4 KB
    __shared__ int   cnt[NN];                                 // 4 KB
    __shared__ unsigned short order[NN];                      // 2 KB pos -> node
    __shared__ unsigned short pos_lds[NN];                    // 2 KB node -> pos
    __shared__ __align__(16) float s_attn2[LL];               // clamp(attn*log2e)
    __shared__ float s_bm[LL];
    __shared__ int   csum[64];
    __shared__ int   s_flag, s_maxlvl;

    const int d    = blockIdx.x;
    const int tid  = threadIdx.x;
    const int wid  = tid >> 6;
    const int lane = tid & 63;
    // round-1 task coords, set A (task tid) and set B (task tid+BT)
    const int niA = tid / NG2,        lgA = tid - niA * NG2;
    const int niB = (tid+BT) / NG2,   lgB = (tid+BT) - niB * NG2;

    const float* atom_d = atom + (size_t)d * NN * LL;
    const int*   pred_d = pred + (size_t)d * NN * PP;
    float*       out_d  = out_all + (size_t)d * NN * LL;

    // ---- W_merge fragments -> registers. Wave w owns nt = min(w,6) ----
    short8 wh[7], wl[7];
    {
        const int r = min(wid, 6)*16 + (lane & 15);
        #pragma unroll
        for (int kt = 0; kt < 7; ++kt) {
            const int k0 = kt*32 + (lane >> 4)*8;
            short8 hh, lo8;
            #pragma unroll
            for (int j = 0; j < 8; ++j) {
                float v = (r < LL && (k0 + j) < 2*LL) ? W_merge[r*2*LL + k0 + j] : 0.f;
                unsigned short a, b;
                split_bf16(v, a, b);
                hh[j] = (short)a; lo8[j] = (short)b;
            }
            wh[kt] = hh; wl[kt] = lo8;
        }
    }

    // ---- init ----
    for (int idx = tid; idx < TMAX * (KP - 2*LL); idx += BT) {
        int rr = idx / (KP - 2*LL), cc = 2*LL + (idx - rr*(KP - 2*LL));
        x_hi[rr][cc] = 0; x_lo[rr][cc] = 0;
    }
    if (tid < LL) {
        s_attn2[tid] = fmaxf(attn_w[tid] * 1.44269504f, 1e-30f);
        s_bm[tid] = b_merge[tid];
    }
    if (tid == 0) { s_flag = 0; s_maxlvl = 0; }
    lvl[tid] = 0; lvl[tid + BT] = 0;

    // ---- preds of my 2 nodes -> registers (global, coalesced) ----
    int mypA[PP], mypB[PP];
    {
        const int4* p4 = (const int4*)(pred_d + tid * PP);
        int4 a = p4[0], b = p4[1];
        mypA[0]=a.x; mypA[1]=a.y; mypA[2]=a.z; mypA[3]=a.w;
        mypA[4]=b.x; mypA[5]=b.y; mypA[6]=b.z; mypA[7]=b.w;
        const int4* q4 = (const int4*)(pred_d + (tid + BT) * PP);
        int4 c = q4[0], e = q4[1];
        mypB[0]=c.x; mypB[1]=c.y; mypB[2]=c.z; mypB[3]=c.w;
        mypB[4]=e.x; mypB[5]=e.y; mypB[6]=e.z; mypB[7]=e.w;
    }
    __syncthreads();

    // ---- 1. level relaxation: 2 nodes/thread, double monotone sweep ----
    for (int it = 1; it <= NN; ++it) {
        bool ch = false;
        #pragma unroll
        for (int rep = 0; rep < 2; ++rep) {
            int mxA = -1, mxB = -1;
            #pragma unroll
            for (int q = 0; q < PP; ++q) {
                if (mypA[q] >= 0) mxA = max(mxA, lvl[mypA[q]]);
                if (mypB[q] >= 0) mxB = max(mxB, lvl[mypB[q]]);
            }
            if (mxA + 1 != lvl[tid])      { lvl[tid]      = mxA + 1; ch = true; }
            if (mxB + 1 != lvl[tid + BT]) { lvl[tid + BT] = mxB + 1; ch = true; }
        }
        if (ch) s_flag = it;
        __syncthreads();
        int f = s_flag;
        __syncthreads();
        if (f != it) break;
    }
    atomicMax(&s_maxlvl, max(lvl[tid], lvl[tid + BT]));

    // ---- 2. counting sort by level (order + pos) ----
    cnt[tid] = 0; cnt[tid + BT] = 0;
    __syncthreads();
    atomicAdd(&cnt[lvl[tid]], 1);
    atomicAdd(&cnt[lvl[tid + BT]], 1);
    __syncthreads();
    if (tid < 64) { int s = 0; for (int i = 0; i < 16; ++i) s += cnt[tid*16 + i]; csum[tid] = s; }
    __syncthreads();
    if (tid == 0) { int run = 0; for (int t = 0; t < 64; ++t) { int c = csum[t]; csum[t] = run; run += c; } }
    __syncthreads();
    if (tid < 64) {
        int run = csum[tid];
        for (int i = 0; i < 16; ++i) { int c = cnt[tid*16 + i]; cnt[tid*16 + i] = run; run += c; }
    }
    __syncthreads();
    {
        int pos = atomicAdd(&cnt[lvl[tid]], 1);
        order[pos] = (unsigned short)tid;        pos_lds[tid] = (unsigned short)pos;
        pos = atomicAdd(&cnt[lvl[tid + BT]], 1);
        order[pos] = (unsigned short)(tid + BT); pos_lds[tid + BT] = (unsigned short)pos;
    }
    __syncthreads();

    // ---- 2b. position-space graph: ppos_lds[pos][q] (0xFFFF = none) ----
    {
        unsigned short tA[PP], tB[PP];
        #pragma unroll
        for (int q = 0; q < PP; ++q) {
            tA[q] = (mypA[q] < 0) ? (unsigned short)0xFFFFu : pos_lds[mypA[q]];
            tB[q] = (mypB[q] < 0) ? (unsigned short)0xFFFFu : pos_lds[mypB[q]];
        }
        int pA = pos_lds[tid], pB = pos_lds[tid + BT];
        *(short4v*)&ppos_lds[pA][0] = (short4v){(short)tA[0],(short)tA[1],(short)tA[2],(short)tA[3]};
        *(short4v*)&ppos_lds[pA][4] = (short4v){(short)tA[4],(short)tA[5],(short)tA[6],(short)tA[7]};
        *(short4v*)&ppos_lds[pB][0] = (short4v){(short)tB[0],(short)tB[1],(short)tB[2],(short)tB[3]};
        *(short4v*)&ppos_lds[pB][4] = (short4v){(short)tB[4],(short)tB[5],(short)tB[6],(short)tB[7]};
    }
    __syncthreads();

    const float2 awA = *(const float2*)&s_attn2[lgA * 2];
    const float2 awB = *(const float2*)&s_attn2[lgB * 2];

    // ---- 3. level-0 (root) via W_single; write out_d + out_lds[1] ----
    {
        int nroots = cnt[0];
        for (int task = tid; task < nroots * LL; task += BT) {
            int ni = task / LL, r = task - ni * LL;
            int n = order[ni];
            float acc = b_single[r];
            const float* feat = atom_d + n * LL;
            const float* wr = W_single + r * LL;
            #pragma unroll 8
            for (int l = 0; l < LL; ++l) acc = fmaf(wr[l], feat[l], acc);
            float v = fmaxf(acc, 0.f);
            out_d[n * LL + r] = v;
            if (ni < TMAX) out_lds[1][ni][r] = v;
            if (n == NN - 1) last_buf[d * LL + r] = v;
        }
    }
    __syncthreads();

    const int maxlvl = s_maxlvl;

    // ---- prefetch state: round-1 tasks (tid) and (tid+BT) of NEXT tile ----
    float2  pfA_po[PP], pfB_po[PP];
    unsigned pfA_fth = 0, pfA_ftl = 0, pfB_fth = 0, pfB_ftl = 0;
    short8  pf_ppsA = {0,0,0,0,0,0,0,0}, pf_ppsB = {0,0,0,0,0,0,0,0};

    // Issue gathers for task TASK of tile [NT0,NT0+NTC). CT0 = current tile
    // start (pp >= CT0: fresh/invalid -> NEGBIG, resolved in A). PT0/PBUF:
    // previous tile start + its out_lds buffer.
#define PREFETCH_SET(PPS, PO, FTH, FTL, TASK, NI, LG, NT0, NTC, CT0, PT0, PBUF) do { \
        if ((TASK) < (NTC) * NG2) {                                            \
            int n_ = order[(NT0) + (NI)];                                      \
            float2 ft_ = *(const float2*)&atom_d[n_ * LL + (LG) * 2];          \
            unsigned short a0_, a1_, b0_, b1_;                                 \
            split_bf16(ft_.x, a0_, b0_); split_bf16(ft_.y, a1_, b1_);          \
            FTH = (unsigned)a0_ | ((unsigned)a1_ << 16);                       \
            FTL = (unsigned)b0_ | ((unsigned)b1_ << 16);                       \
            PPS = *(const short8*)&ppos_lds[(NT0) + (NI)][0];                  \
            _Pragma("unroll")                                                  \
            for (int q_ = 0; q_ < PP; ++q_) {                                  \
                int pp_ = (unsigned short)PPS[q_];                             \
                if (pp_ >= (CT0)) {                                            \
                    PO[q_] = (float2){NEGBIG, NEGBIG};                         \
                } else if (pp_ >= (PT0)) {                                     \
                    PO[q_] = *(const float2*)&out_lds[PBUF][pp_ - (PT0)][(LG) * 2]; \
                } else {                                                       \
                    PO[q_] = *(const float2*)&out_d[(int)order[pp_] * LL + (LG) * 2]; \
                }                                                              \
            }                                                                  \
        }                                                                      \
    } while (0)

    int pt0 = 0, ptc = cnt[0];
    int wbuf = 0;

    // prologue: first tile of level 1 (all preds level-0 -> out_lds[1])
    if (maxlvl >= 1) {
        int s1 = cnt[0];
        int ntc0 = min(TMAX, cnt[1] - s1);
        PREFETCH_SET(pf_ppsA, pfA_po, pfA_fth, pfA_ftl, tid,      niA, lgA, s1, ntc0, s1, 0, 1);
        PREFETCH_SET(pf_ppsB, pfB_po, pfB_fth, pfB_ftl, tid + BT, niB, lgB, s1, ntc0, s1, 0, 1);
    }

    // ---- 4. main level loop ----
    for (int L = 1; L <= maxlvl; ++L) {
        const int s = cnt[L - 1], e = cnt[L];
        for (int t0 = s; t0 < e; t0 += TMAX) {
            const int tc = min(TMAX, e - t0);
            const int ntask = tc * NG2;
            const int pcopy = ptc * NGC;
            const int rbuf = wbuf ^ 1;

            // ---------- phase A ----------
            // deferred global store of PREVIOUS tile (drained at A->B barrier)
            for (int ct = tid; ct < pcopy; ct += BT) {
                int ci = ct / NGC, lgc = ct - ci * NGC;
                *(float4*)&out_d[(int)order[pt0 + ci] * LL + lgc * 4] =
                    *(const float4*)&out_lds[rbuf][ci][lgc * 4];
            }
            // round 1, set A (task tid): LDS + VALU only
            if (tid < ntask) {
                float2 num = {0.f, 0.f}, den = {0.f, 0.f};
                #pragma unroll
                for (int q = 0; q < PP; ++q) {
                    int pp = (unsigned short)pf_ppsA[q];
                    bool fresh = (pp >= pt0) && (pp < t0);
                    int slot = fresh ? (pp - pt0) : 0;
                    float2 lv = *(const float2*)&out_lds[rbuf][slot][lgA * 2];
                    float2 v; v.x = fresh ? lv.x : pfA_po[q].x;
                              v.y = fresh ? lv.y : pfA_po[q].y;
                    acc2(num, den, awA, v);
                }
                store_x2(niA, lgA, num, den, pfA_fth, pfA_ftl, x_hi, x_lo);
            }
            // round 2, set B (task tid+BT)
            if (tid + BT < ntask) {
                float2 num = {0.f, 0.f}, den = {0.f, 0.f};
                #pragma unroll
                for (int q = 0; q < PP; ++q) {
                    int pp = (unsigned short)pf_ppsB[q];
                    bool fresh = (pp >= pt0) && (pp < t0);
                    int slot = fresh ? (pp - pt0) : 0;
                    float2 lv = *(const float2*)&out_lds[rbuf][slot][lgB * 2];
                    float2 v; v.x = fresh ? lv.x : pfB_po[q].x;
                              v.y = fresh ? lv.y : pfB_po[q].y;
                    acc2(num, den, awB, v);
                }
                store_x2(niB, lgB, num, den, pfB_fth, pfB_ftl, x_hi, x_lo);
            }
            // rounds 3+ (tc > 19 only): direct path (old: global; prev: rbuf)
            for (int task = tid + 2*BT; task < ntask; task += BT) {
                int ni = task / NG2, lg = task - ni * NG2;
                short8 pps = *(const short8*)&ppos_lds[t0 + ni][0];
                float2 aw = *(const float2*)&s_attn2[lg * 2];
                float2 gv[PP];
                #pragma unroll
                for (int q = 0; q < PP; ++q) {
                    int pp = (unsigned short)pps[q];
                    bool old = pp < pt0;
                    int row = old ? (int)order[pp] : 0;
                    gv[q] = *(const float2*)&out_d[row * LL + lg * 2];
                }
                float2 num = {0.f, 0.f}, den = {0.f, 0.f};
                #pragma unroll
                for (int q = 0; q < PP; ++q) {
                    int pp = (unsigned short)pps[q];
                    bool on   = pp < t0;          // valid (preds always < t0)
                    bool prev = pp >= pt0;        // in rbuf
                    int slot = (prev && on) ? (pp - pt0) : 0;
                    float2 lv = *(const float2*)&out_lds[rbuf][slot][lg * 2];
                    float2 v; v.x = prev ? lv.x : gv[q].x;
                              v.y = prev ? lv.y : gv[q].y;
                    acc2m(num, den, aw, v, on);
                }
                int n = order[t0 + ni];
                float2 ft = *(const float2*)&atom_d[n * LL + lg * 2];
                unsigned short a0, a1, b0, b1;
                split_bf16(ft.x, a0, b0); split_bf16(ft.y, a1, b1);
                unsigned fth = (unsigned)a0 | ((unsigned)a1 << 16);
                unsigned ftl = (unsigned)b0 | ((unsigned)b1 << 16);
                store_x2(ni, lg, num, den, fth, ftl, x_hi, x_lo);
            }
            __syncthreads();   // FULL: x visible; copy stores drained

            // ---------- phase B ----------
            // next tile's prefetch first (loads fly under MFMA and across
            // the raw barrier into next A)
            {
                int nt0 = 0, ntc = 0;
                if (t0 + TMAX < e)        { nt0 = t0 + TMAX; ntc = min(TMAX, e - nt0); }
                else if (L + 1 <= maxlvl) { nt0 = e;         ntc = min(TMAX, cnt[L + 1] - e); }
                PREFETCH_SET(pf_ppsA, pfA_po, pfA_fth, pfA_ftl, tid,      niA, lgA, nt0, ntc, t0, pt0, rbuf);
                PREFETCH_SET(pf_ppsB, pfB_po, pfB_fth, pfB_ftl, tid + BT, niB, lgB, nt0, ntc, t0, pt0, rbuf);
            }

            if (wid < 7) {
                const int mts = (tc + 15) >> 4;
                const int kg = (lane >> 4) * 8;
                const int r0 = wid*16 + (lane & 15);
                for (int mt = 0; mt < mts; ++mt) {
                    const int row_a = mt*16 + (lane & 15);
                    f32x4 a0 = {0.f,0.f,0.f,0.f}, b0 = {0.f,0.f,0.f,0.f}, c0 = {0.f,0.f,0.f,0.f};
                    #pragma unroll
                    for (int kt = 0; kt < 7; ++kt) {
                        const int k0 = kt*32 + kg;
                        short8 ah = *(const short8*)&x_hi[row_a][k0];
                        short8 al = *(const short8*)&x_lo[row_a][k0];
                        a0 = MFMA(ah, wh[kt], a0);
                        b0 = MFMA(ah, wl[kt], b0);
                        c0 = MFMA(al, wh[kt], c0);
                    }
                    f32x4 acc = a0 + b0 + c0;
                    if (r0 < LL) {
                        #pragma unroll
                        for (int j = 0; j < 4; ++j) {
                            int ni = mt*16 + (lane >> 4)*4 + j;
                            if (ni < tc) {
                                float v = fmaxf(acc[j] + s_bm[r0], 0.f);
                                out_lds[wbuf][ni][r0] = v;      // LDS only
                                int n = order[t0 + ni];
                                if (n == NN - 1) last_buf[d*LL + r0] = v;
                            }
                        }
                    }
                }
            }
            BAR_RAW();   // lgkm-only: out_lds visible; prefetch stays in flight
            pt0 = t0; ptc = tc; wbuf ^= 1;
        }
    }
#undef PREFETCH_SET
}

// Cross-DAG softmax pool + final classifier. Single block.
__global__ __launch_bounds__(256) void final_pool_kernel(
    const float* __restrict__ last_buf,  // [DN][LL]
    const float* __restrict__ dag_w,     // [LL]
    const float* __restrict__ W_final,   // [CLS][LL]
    const float* __restrict__ b_final,   // [CLS]
    float* __restrict__ out)             // [CLS]
{
    __shared__ float s_pooled[LL];
    const int tid = threadIdx.x;

    if (tid < LL) {
        float dw = dag_w[tid];
        float m = -1e30f;
        #pragma unroll 8
        for (int dd = 0; dd < DN; ++dd)
            m = fmaxf(m, dw * last_buf[dd * LL + tid]);
        float den = 0.f, num = 0.f;
        #pragma unroll 8
        for (int dd = 0; dd < DN; ++dd) {
            float v = last_buf[dd * LL + tid];
            float e = __expf(dw * v - m);
            den += e;
            num = fmaf(e, v, num);
        }
        s_pooled[tid] = num / den;
    }
    __syncthreads();

    for (int c = tid; c < CLS; c += 256) {
        float acc = b_final[c];
        const float* wr = W_final + c * LL;
        #pragma unroll 8
        for (int l = 0; l < LL; ++l) acc = fmaf(wr[l], s_pooled[l], acc);
        out[c] = acc;
    }
}

extern "C" void kernel_launch(void* const* d_in, const int* in_sizes, int n_in,
                              void* d_out, int out_size, void* d_ws, size_t ws_size,
                              hipStream_t stream) {
    const float* atom     = (const float*)d_in[0];
    const int*   pred     = (const int*)  d_in[1];
    const float* W_single = (const float*)d_in[2];
    const float* b_single = (const float*)d_in[3];
    const float* W_merge  = (const float*)d_in[4];
    const float* b_merge  = (const float*)d_in[5];
    const float* attn_w   = (const float*)d_in[6];
    const float* dag_w    = (const float*)d_in[7];
    const float* W_final  = (const float*)d_in[8];
    const float* b_final  = (const float*)d_in[9];
    float* out = (float*)d_out;

    float* out_all  = (float*)d_ws;                       // [DN][NN][LL]
    float* last_buf = out_all + (size_t)DN * NN * LL;     // [DN][LL]

    dag_level_kernel<<<DN, BT, 0, stream>>>(atom, pred, W_single, b_single,
                                            W_merge, b_merge, attn_w,
                                            out_all, last_buf);
    final_pool_kernel<<<1, 256, 0, stream>>>(last_buf, dag_w, W_final, b_final, out);
}

// Round 16
// 344.841 us; speedup vs baseline: 1.1625x; 1.1222x over previous
//
#include <hip/hip_runtime.h>

#define DN  256   // DAGs
#define NN  1024  // nodes per DAG
#define PP  8     // max predecessors
#define LL  104   // feature dim
#define CLS 500   // classes
#define BT  512   // threads per block (8 waves)
#define TMAX 64   // node tile per level pass
#define KP  232   // padded K stride in bf16 elems
#define NG  26    // float4 feature groups (104/4)
#define OLP 108   // out_lds row pad (432B rows)
#define NEGBIG -3.0e38f

typedef __attribute__((ext_vector_type(8))) short short8;
typedef __attribute__((ext_vector_type(4))) short short4v;
typedef __attribute__((ext_vector_type(4))) float f32x4;

#define MFMA(a, b, c) __builtin_amdgcn_mfma_f32_16x16x32_bf16((a), (b), (c), 0, 0, 0)

// Raw barrier: LDS-visibility only; vmcnt NOT drained.
#define BAR_RAW() do {                                              \
    __builtin_amdgcn_sched_barrier(0);                              \
    asm volatile("s_waitcnt lgkmcnt(0)" ::: "memory");              \
    __builtin_amdgcn_s_barrier();                                   \
    __builtin_amdgcn_sched_barrier(0);                              \
} while (0)

__device__ __forceinline__ void split_bf16(float x, unsigned short& h, unsigned short& l) {
    unsigned u = __float_as_uint(x);
    h = (unsigned short)(u >> 16);
    float hf = __uint_as_float(u & 0xFFFF0000u);
    l = (unsigned short)(__float_as_uint(x - hf) >> 16);
}

// softmax over preds + split-bf16 + x store. Invalid preds carry pv = -3e38
// so exp2(aw2*pv) == 0 exactly (aw2 clamped >= 1e-30) -> no masking needed.
__device__ __forceinline__ void sm_store3(int ni, int lg, float4 aw4,
    const float4 pv[PP], float4 ft,
    unsigned short (*xh)[KP], unsigned short (*xl)[KP])
{
    float awv[4] = {aw4.x, aw4.y, aw4.z, aw4.w};
    float ftv[4] = {ft.x, ft.y, ft.z, ft.w};
    unsigned short oh[4], ol[4], fh[4], fl[4];
    #pragma unroll
    for (int f = 0; f < 4; ++f) {
        float den = 0.f, num = 0.f;
        #pragma unroll
        for (int q = 0; q < PP; ++q) {
            float pvq = ((const float*)&pv[q])[f];
            float e2 = exp2f(awv[f] * pvq);
            den += e2;
            num = fmaf(e2, pvq, num);
        }
        float agg = __fdividef(num, den);
        split_bf16(agg,    oh[f], ol[f]);
        split_bf16(ftv[f], fh[f], fl[f]);
    }
    *(short4v*)&xh[ni][lg*4] = (short4v){(short)oh[0],(short)oh[1],(short)oh[2],(short)oh[3]};
    *(short4v*)&xl[ni][lg*4] = (short4v){(short)ol[0],(short)ol[1],(short)ol[2],(short)ol[3]};
    *(short4v*)&xh[ni][LL + lg*4] = (short4v){(short)fh[0],(short)fh[1],(short)fh[2],(short)fh[3]};
    *(short4v*)&xl[ni][LL + lg*4] = (short4v){(short)fl[0],(short)fl[1],(short)fl[2],(short)fl[3]};
}

// One block per DAG, 8 waves. Level-scheduled split-bf16 MFMA GEMM per level.
// Double-buffered out_lds; prev-tile preds from LDS; old preds prefetched in
// phase B and kept in flight across a RAW (lgkm-only) B->A barrier.
__global__ __launch_bounds__(BT, 2) void dag_level_kernel(
    const float* __restrict__ atom,      // [DN][NN][LL]
    const int*   __restrict__ pred,      // [DN][NN][PP]
    const float* __restrict__ W_single,  // [LL][LL]
    const float* __restrict__ b_single,  // [LL]
    const float* __restrict__ W_merge,   // [LL][2*LL]
    const float* __restrict__ b_merge,   // [LL]
    const float* __restrict__ attn_w,    // [LL]
    float* __restrict__ out_all,         // ws: [DN][NN][LL]
    float* __restrict__ last_buf)        // ws: [DN][LL]
{
    __shared__ __align__(16) unsigned short x_hi[TMAX][KP];   // 29 KB
    __shared__ __align__(16) unsigned short x_lo[TMAX][KP];   // 29 KB
    __shared__ __align__(16) unsigned short ppos_lds[NN][PP]; // 16 KB pred positions
    __shared__ __align__(16) float out_lds[2][TMAX][OLP];     // 55 KB dbuf tile outputs
    __shared__ int   lvl[NN];                                 // 4 KB
    __shared__ int   cnt[NN];                                 // 4 KB
    __shared__ unsigned short order[NN];                      // 2 KB pos -> node
    __shared__ unsigned short pos_lds[NN];                    // 2 KB node -> pos
    __shared__ __align__(16) float s_attn2[LL];               // clamp(attn*log2e)
    __shared__ float s_bm[LL];
    __shared__ int   csum[64];
    __shared__ int   s_flag, s_maxlvl;

    const int d    = blockIdx.x;
    const int tid  = threadIdx.x;
    const int wid  = tid >> 6;
    const int lane = tid & 63;
    const int my_ni = tid / NG;
    const int my_lg = tid - my_ni * NG;

    const float* atom_d = atom + (size_t)d * NN * LL;
    const int*   pred_d = pred + (size_t)d * NN * PP;
    float*       out_d  = out_all + (size_t)d * NN * LL;

    // ---- W_merge fragments -> registers. Wave w owns nt = min(w,6) ----
    short8 wh[7], wl[7];
    {
        const int r = min(wid, 6)*16 + (lane & 15);
        #pragma unroll
        for (int kt = 0; kt < 7; ++kt) {
            const int k0 = kt*32 + (lane >> 4)*8;
            short8 hh, lo8;
            #pragma unroll
            for (int j = 0; j < 8; ++j) {
                float v = (r < LL && (k0 + j) < 2*LL) ? W_merge[r*2*LL + k0 + j] : 0.f;
                unsigned short a, b;
                split_bf16(v, a, b);
                hh[j] = (short)a; lo8[j] = (short)b;
            }
            wh[kt] = hh; wl[kt] = lo8;
        }
    }

    // ---- init ----
    for (int idx = tid; idx < TMAX * (KP - 2*LL); idx += BT) {
        int rr = idx / (KP - 2*LL), cc = 2*LL + (idx - rr*(KP - 2*LL));
        x_hi[rr][cc] = 0; x_lo[rr][cc] = 0;
    }
    if (tid < LL) {
        s_attn2[tid] = fmaxf(attn_w[tid] * 1.44269504f, 1e-30f);
        s_bm[tid] = b_merge[tid];
    }
    if (tid == 0) { s_flag = 0; s_maxlvl = 0; }
    lvl[tid] = 0; lvl[tid + BT] = 0;

    // ---- preds of my 2 nodes -> registers (global, coalesced) ----
    int mypA[PP], mypB[PP];
    {
        const int4* p4 = (const int4*)(pred_d + tid * PP);
        int4 a = p4[0], b = p4[1];
        mypA[0]=a.x; mypA[1]=a.y; mypA[2]=a.z; mypA[3]=a.w;
        mypA[4]=b.x; mypA[5]=b.y; mypA[6]=b.z; mypA[7]=b.w;
        const int4* q4 = (const int4*)(pred_d + (tid + BT) * PP);
        int4 c = q4[0], e = q4[1];
        mypB[0]=c.x; mypB[1]=c.y; mypB[2]=c.z; mypB[3]=c.w;
        mypB[4]=e.x; mypB[5]=e.y; mypB[6]=e.z; mypB[7]=e.w;
    }
    __syncthreads();

    // ---- 1. level relaxation: 2 nodes/thread, double monotone sweep ----
    for (int it = 1; it <= NN; ++it) {
        bool ch = false;
        #pragma unroll
        for (int rep = 0; rep < 2; ++rep) {
            int mxA = -1, mxB = -1;
            #pragma unroll
            for (int q = 0; q < PP; ++q) {
                if (mypA[q] >= 0) mxA = max(mxA, lvl[mypA[q]]);
                if (mypB[q] >= 0) mxB = max(mxB, lvl[mypB[q]]);
            }
            if (mxA + 1 != lvl[tid])      { lvl[tid]      = mxA + 1; ch = true; }
            if (mxB + 1 != lvl[tid + BT]) { lvl[tid + BT] = mxB + 1; ch = true; }
        }
        if (ch) s_flag = it;
        __syncthreads();
        int f = s_flag;
        __syncthreads();
        if (f != it) break;
    }
    atomicMax(&s_maxlvl, max(lvl[tid], lvl[tid + BT]));

    // ---- 2. counting sort by level (order + pos) ----
    cnt[tid] = 0; cnt[tid + BT] = 0;
    __syncthreads();
    atomicAdd(&cnt[lvl[tid]], 1);
    atomicAdd(&cnt[lvl[tid + BT]], 1);
    __syncthreads();
    if (tid < 64) { int s = 0; for (int i = 0; i < 16; ++i) s += cnt[tid*16 + i]; csum[tid] = s; }
    __syncthreads();
    if (tid == 0) { int run = 0; for (int t = 0; t < 64; ++t) { int c = csum[t]; csum[t] = run; run += c; } }
    __syncthreads();
    if (tid < 64) {
        int run = csum[tid];
        for (int i = 0; i < 16; ++i) { int c = cnt[tid*16 + i]; cnt[tid*16 + i] = run; run += c; }
    }
    __syncthreads();
    {
        int pos = atomicAdd(&cnt[lvl[tid]], 1);
        order[pos] = (unsigned short)tid;        pos_lds[tid] = (unsigned short)pos;
        pos = atomicAdd(&cnt[lvl[tid + BT]], 1);
        order[pos] = (unsigned short)(tid + BT); pos_lds[tid + BT] = (unsigned short)pos;
    }
    __syncthreads();

    // ---- 2b. position-space graph: ppos_lds[pos][q] (0xFFFF = none) ----
    {
        unsigned short tA[PP], tB[PP];
        #pragma unroll
        for (int q = 0; q < PP; ++q) {
            tA[q] = (mypA[q] < 0) ? (unsigned short)0xFFFFu : pos_lds[mypA[q]];
            tB[q] = (mypB[q] < 0) ? (unsigned short)0xFFFFu : pos_lds[mypB[q]];
        }
        int pA = pos_lds[tid], pB = pos_lds[tid + BT];
        *(short4v*)&ppos_lds[pA][0] = (short4v){(short)tA[0],(short)tA[1],(short)tA[2],(short)tA[3]};
        *(short4v*)&ppos_lds[pA][4] = (short4v){(short)tA[4],(short)tA[5],(short)tA[6],(short)tA[7]};
        *(short4v*)&ppos_lds[pB][0] = (short4v){(short)tB[0],(short)tB[1],(short)tB[2],(short)tB[3]};
        *(short4v*)&ppos_lds[pB][4] = (short4v){(short)tB[4],(short)tB[5],(short)tB[6],(short)tB[7]};
    }
    __syncthreads();

    const float4 my_aw = *(const float4*)&s_attn2[my_lg * 4];

    // ---- 3. level-0 (root) via W_single; write out_d + out_lds[1] ----
    {
        int nroots = cnt[0];
        for (int task = tid; task < nroots * LL; task += BT) {
            int ni = task / LL, r = task - ni * LL;
            int n = order[ni];
            float acc = b_single[r];
            const float* feat = atom_d + n * LL;
            const float* wr = W_single + r * LL;
            #pragma unroll 8
            for (int l = 0; l < LL; ++l) acc = fmaf(wr[l], feat[l], acc);
            float v = fmaxf(acc, 0.f);
            out_d[n * LL + r] = v;
            if (ni < TMAX) out_lds[1][ni][r] = v;
            if (n == NN - 1) last_buf[d * LL + r] = v;
        }
    }
    __syncthreads();

    const int maxlvl = s_maxlvl;

    // ---- prefetch state for round-1 task (tid) of the NEXT tile ----
    float4  pf_po[PP];               // old preds: global; prev: LDS; invalid: -3e38
    float4  pf_ft = {0.f,0.f,0.f,0.f};
    short8  pf_pps = {0,0,0,0,0,0,0,0};

    // CT0 = current tile start (pp >= CT0: fresh/invalid -> resolved in A).
    // PT0/PBUF: previous tile start + its out_lds buffer.
#define PREFETCH(NT0, NTC, CT0, PT0, PBUF) do {                                \
        if (tid < (NTC) * NG) {                                                \
            int n_ = order[(NT0) + my_ni];                                     \
            pf_ft  = *(const float4*)&atom_d[n_ * LL + my_lg * 4];             \
            pf_pps = *(const short8*)&ppos_lds[(NT0) + my_ni][0];              \
            _Pragma("unroll")                                                  \
            for (int q_ = 0; q_ < PP; ++q_) {                                  \
                int pp_ = (unsigned short)pf_pps[q_];                          \
                if (pp_ >= (CT0)) {                                            \
                    pf_po[q_] = (float4){NEGBIG, NEGBIG, NEGBIG, NEGBIG};      \
                } else if (pp_ >= (PT0)) {                                     \
                    pf_po[q_] = *(const float4*)&out_lds[PBUF][pp_ - (PT0)][my_lg * 4]; \
                } else {                                                       \
                    pf_po[q_] = *(const float4*)&out_d[(int)order[pp_] * LL + my_lg * 4]; \
                }                                                              \
            }                                                                  \
        }                                                                      \
    } while (0)

    int pt0 = 0, ptc = cnt[0];
    int wbuf = 0;

    // prologue: first tile of level 1 (all preds level-0 -> out_lds[1])
    if (maxlvl >= 1) {
        int s1 = cnt[0];
        PREFETCH(s1, min(TMAX, cnt[1] - s1), s1, 0, 1);
    }

    // ---- 4. main level loop ----
    for (int L = 1; L <= maxlvl; ++L) {
        const int s = cnt[L - 1], e = cnt[L];
        for (int t0 = s; t0 < e; t0 += TMAX) {
            const int tc = min(TMAX, e - t0);
            const int ntask = tc * NG;
            const int pcopy = ptc * NG;
            const int rbuf = wbuf ^ 1;

            // ---------- phase A ----------
            // deferred global store of PREVIOUS tile: issue FIRST (acks hide
            // under softmax; drained at the full A->B barrier)
            for (int ct = tid; ct < pcopy; ct += BT) {
                int ci = ct / NG, lg2 = ct - ci * NG;
                *(float4*)&out_d[(int)order[pt0 + ci] * LL + lg2 * 4] =
                    *(const float4*)&out_lds[rbuf][ci][lg2 * 4];
            }
            // round 1: LDS + VALU only (prefetch regs + out_lds prev buffer)
            if (tid < ntask) {
                float4 pv[PP];
                #pragma unroll
                for (int q = 0; q < PP; ++q) {
                    int pp = (unsigned short)pf_pps[q];
                    bool fresh = (pp >= pt0) && (pp < t0);
                    int slot = fresh ? (pp - pt0) : 0;
                    float4 lv = *(const float4*)&out_lds[rbuf][slot][my_lg * 4];
                    pv[q] = fresh ? lv : pf_po[q];
                }
                sm_store3(my_ni, my_lg, my_aw, pv, pf_ft, x_hi, x_lo);
            }
            // rounds 2+ (tc > 19 only)
            for (int task = tid + BT; task < ntask; task += BT) {
                int ni = task / NG, lg = task - ni * NG;
                short8 pps = *(const short8*)&ppos_lds[t0 + ni][0];
                float4 pv[PP];
                #pragma unroll
                for (int q = 0; q < PP; ++q) {
                    int pp = (unsigned short)pps[q];
                    if (pp >= t0) {          // invalid (preds always < t0)
                        pv[q] = (float4){NEGBIG, NEGBIG, NEGBIG, NEGBIG};
                    } else if (pp >= pt0) {  // previous tile -> LDS
                        pv[q] = *(const float4*)&out_lds[rbuf][pp - pt0][lg * 4];
                    } else {                 // old -> global (copied >=1 full barrier ago)
                        pv[q] = *(const float4*)&out_d[(int)order[pp] * LL + lg * 4];
                    }
                }
                int n = order[t0 + ni];
                float4 ft = *(const float4*)&atom_d[n * LL + lg * 4];
                float4 aw4 = *(const float4*)&s_attn2[lg * 4];
                sm_store3(ni, lg, aw4, pv, ft, x_hi, x_lo);
            }
            __syncthreads();   // FULL: x visible; copy stores drained

            // ---------- phase B ----------
            // next tile's prefetch first (loads fly under MFMA and across
            // the raw barrier into next A)
            {
                int nt0 = 0, ntc = 0;
                if (t0 + TMAX < e)        { nt0 = t0 + TMAX; ntc = min(TMAX, e - nt0); }
                else if (L + 1 <= maxlvl) { nt0 = e;         ntc = min(TMAX, cnt[L + 1] - e); }
                PREFETCH(nt0, ntc, t0, pt0, rbuf);
            }

            if (wid < 7) {
                const int mts = (tc + 15) >> 4;
                const int kg = (lane >> 4) * 8;
                const int r0 = wid*16 + (lane & 15);
                for (int mt = 0; mt < mts; ++mt) {
                    const int row_a = mt*16 + (lane & 15);
                    f32x4 a0 = {0.f,0.f,0.f,0.f}, b0 = {0.f,0.f,0.f,0.f}, c0 = {0.f,0.f,0.f,0.f};
                    #pragma unroll
                    for (int kt = 0; kt < 7; ++kt) {
                        const int k0 = kt*32 + kg;
                        short8 ah = *(const short8*)&x_hi[row_a][k0];
                        short8 al = *(const short8*)&x_lo[row_a][k0];
                        a0 = MFMA(ah, wh[kt], a0);
                        b0 = MFMA(ah, wl[kt], b0);
                        c0 = MFMA(al, wh[kt], c0);
                    }
                    f32x4 acc = a0 + b0 + c0;
                    if (r0 < LL) {
                        #pragma unroll
                        for (int j = 0; j < 4; ++j) {
                            int ni = mt*16 + (lane >> 4)*4 + j;
                            if (ni < tc) {
                                float v = fmaxf(acc[j] + s_bm[r0], 0.f);
                                out_lds[wbuf][ni][r0] = v;      // LDS only
                                int n = order[t0 + ni];
                                if (n == NN - 1) last_buf[d*LL + r0] = v;
                            }
                        }
                    }
                }
            }
            BAR_RAW();   // lgkm-only: out_lds visible; prefetch stays in flight
            pt0 = t0; ptc = tc; wbuf ^= 1;
        }
    }
#undef PREFETCH
}

// Cross-DAG softmax pool: 104 features x 4 DAG-groups of 64, LDS combine.
__global__ __launch_bounds__(512) void pool_kernel(
    const float* __restrict__ last_buf,  // [DN][LL]
    const float* __restrict__ dag_w,     // [LL]
    float* __restrict__ pooled)          // ws: [LL]
{
    __shared__ float sm[4][LL], sden[4][LL], snum[4][LL];
    const int t = threadIdx.x;

    if (t < LL * 4) {
        const int l = t >> 2, g = t & 3;
        const float dw = dag_w[l];
        const float* p = last_buf + (size_t)g * 64 * LL + l;
        float m = -1e30f;
        #pragma unroll 8
        for (int i = 0; i < 64; ++i) m = fmaxf(m, dw * p[i * LL]);
        float den = 0.f, num = 0.f;
        #pragma unroll 8
        for (int i = 0; i < 64; ++i) {
            float v = p[i * LL];
            float e = __expf(fmaf(dw, v, -m));
            den += e;
            num = fmaf(e, v, num);
        }
        sm[g][l] = m; sden[g][l] = den; snum[g][l] = num;
    }
    __syncthreads();
    if (t < LL) {
        float M = fmaxf(fmaxf(sm[0][t], sm[1][t]), fmaxf(sm[2][t], sm[3][t]));
        float den = 0.f, num = 0.f;
        #pragma unroll
        for (int g = 0; g < 4; ++g) {
            float s = __expf(sm[g][t] - M);
            den = fmaf(sden[g][t], s, den);
            num = fmaf(snum[g][t], s, num);
        }
        pooled[t] = __fdividef(num, den);
    }
}

// Final classifier: 8 blocks x 64 threads, one class per thread.
__global__ __launch_bounds__(64) void classifier_kernel(
    const float* __restrict__ pooled,    // ws: [LL]
    const float* __restrict__ W_final,   // [CLS][LL]
    const float* __restrict__ b_final,   // [CLS]
    float* __restrict__ out)             // [CLS]
{
    __shared__ float sp[LL];
    const int t = threadIdx.x;
    for (int i = t; i < LL; i += 64) sp[i] = pooled[i];
    __syncthreads();
    const int c = blockIdx.x * 64 + t;
    if (c < CLS) {
        float acc = b_final[c];
        const float* wr = W_final + c * LL;
        #pragma unroll 8
        for (int l = 0; l < LL; ++l) acc = fmaf(wr[l], sp[l], acc);
        out[c] = acc;
    }
}

extern "C" void kernel_launch(void* const* d_in, const int* in_sizes, int n_in,
                              void* d_out, int out_size, void* d_ws, size_t ws_size,
                              hipStream_t stream) {
    const float* atom     = (const float*)d_in[0];
    const int*   pred     = (const int*)  d_in[1];
    const float* W_single = (const float*)d_in[2];
    const float* b_single = (const float*)d_in[3];
    const float* W_merge  = (const float*)d_in[4];
    const float* b_merge  = (const float*)d_in[5];
    const float* attn_w   = (const float*)d_in[6];
    const float* dag_w    = (const float*)d_in[7];
    const float* W_final  = (const float*)d_in[8];
    const float* b_final  = (const float*)d_in[9];
    float* out = (float*)d_out;

    float* out_all  = (float*)d_ws;                       // [DN][NN][LL]
    float* last_buf = out_all + (size_t)DN * NN * LL;     // [DN][LL]
    float* pooled   = last_buf + (size_t)DN * LL;         // [LL]

    dag_level_kernel<<<DN, BT, 0, stream>>>(atom, pred, W_single, b_single,
                                            W_merge, b_merge, attn_w,
                                            out_all, last_buf);
    pool_kernel<<<1, 512, 0, stream>>>(last_buf, dag_w, pooled);
    classifier_kernel<<<(CLS + 63) / 64, 64, 0, stream>>>(pooled, W_final, b_final, out);
}

// Round 17
// 320.969 us; speedup vs baseline: 1.2490x; 1.0744x over previous
//
#include <hip/hip_runtime.h>

#define DN  256   // DAGs
#define NN  1024  // nodes per DAG
#define PP  8     // max predecessors
#define LL  104   // feature dim
#define CLS 500   // classes
#define BT  512   // threads per block (8 waves)
#define TMAX 64   // node tile per level pass
#define KP  232   // padded K stride in bf16 elems
#define NG  26    // float4 feature groups (104/4)
#define OLP 108   // out_lds row pad (432B rows)
#define NEGBIG -3.0e38f

typedef __attribute__((ext_vector_type(8))) short short8;
typedef __attribute__((ext_vector_type(4))) short short4v;
typedef __attribute__((ext_vector_type(4))) float f32x4;

#define MFMA(a, b, c) __builtin_amdgcn_mfma_f32_16x16x32_bf16((a), (b), (c), 0, 0, 0)

// Raw barrier: LDS-visibility only; vmcnt NOT drained.
#define BAR_RAW() do {                                              \
    __builtin_amdgcn_sched_barrier(0);                              \
    asm volatile("s_waitcnt lgkmcnt(0)" ::: "memory");              \
    __builtin_amdgcn_s_barrier();                                   \
    __builtin_amdgcn_sched_barrier(0);                              \
} while (0)

__device__ __forceinline__ void split_bf16(float x, unsigned short& h, unsigned short& l) {
    unsigned u = __float_as_uint(x);
    h = (unsigned short)(u >> 16);
    float hf = __uint_as_float(u & 0xFFFF0000u);
    l = (unsigned short)(__float_as_uint(x - hf) >> 16);
}

// softmax over preds + split-bf16 + x store. Invalid/skipped preds carry
// pv = -3e38 so raw exp2(aw*pv) == 0 exactly (aw clamped >= 1e-30).
__device__ __forceinline__ void sm_store3(int ni, int lg, float4 aw4,
    const float4 pv[PP], float4 ft,
    unsigned short (*xh)[KP], unsigned short (*xl)[KP])
{
    float awv[4] = {aw4.x, aw4.y, aw4.z, aw4.w};
    float ftv[4] = {ft.x, ft.y, ft.z, ft.w};
    unsigned short oh[4], ol[4], fh[4], fl[4];
    #pragma unroll
    for (int f = 0; f < 4; ++f) {
        float den = 0.f, num = 0.f;
        #pragma unroll
        for (int q = 0; q < PP; ++q) {
            float pvq = ((const float*)&pv[q])[f];
            float e2 = __builtin_amdgcn_exp2f(awv[f] * pvq);   // raw v_exp_f32
            den += e2;
            num = fmaf(e2, pvq, num);
        }
        float agg = __fdividef(num, den);
        split_bf16(agg,    oh[f], ol[f]);
        split_bf16(ftv[f], fh[f], fl[f]);
    }
    *(short4v*)&xh[ni][lg*4] = (short4v){(short)oh[0],(short)oh[1],(short)oh[2],(short)oh[3]};
    *(short4v*)&xl[ni][lg*4] = (short4v){(short)ol[0],(short)ol[1],(short)ol[2],(short)ol[3]};
    *(short4v*)&xh[ni][LL + lg*4] = (short4v){(short)fh[0],(short)fh[1],(short)fh[2],(short)fh[3]};
    *(short4v*)&xl[ni][LL + lg*4] = (short4v){(short)fl[0],(short)fl[1],(short)fl[2],(short)fl[3]};
}

// One block per DAG, 8 waves. Level-scheduled split-bf16 MFMA GEMM per level.
// Double-buffered out_lds (+1 NEGBIG dummy row for branchless select-merge);
// prev-tile preds from LDS; old preds prefetched in phase B and kept in
// flight across a RAW (lgkm-only) B->A barrier.
__global__ __launch_bounds__(BT, 2) void dag_level_kernel(
    const float* __restrict__ atom,      // [DN][NN][LL]
    const int*   __restrict__ pred,      // [DN][NN][PP]
    const float* __restrict__ W_single,  // [LL][LL]
    const float* __restrict__ b_single,  // [LL]
    const float* __restrict__ W_merge,   // [LL][2*LL]
    const float* __restrict__ b_merge,   // [LL]
    const float* __restrict__ attn_w,    // [LL]
    float* __restrict__ out_all,         // ws: [DN][NN][LL]
    float* __restrict__ last_buf)        // ws: [DN][LL]
{
    __shared__ __align__(16) unsigned short x_hi[TMAX][KP];   // 29 KB
    __shared__ __align__(16) unsigned short x_lo[TMAX][KP];   // 29 KB
    __shared__ __align__(16) unsigned short ppos_lds[NN][PP]; // 16 KB pred positions
    __shared__ __align__(16) float out_lds[2][TMAX+1][OLP];   // 56 KB dbuf + dummy row
    __shared__ int   lvl[NN];                                 // 4 KB
    __shared__ int   cnt[NN];                                 // 4 KB
    __shared__ unsigned short order[NN];                      // 2 KB pos -> node
    __shared__ unsigned short pos_lds[NN];                    // 2 KB node -> pos
    __shared__ __align__(16) float s_attn2[LL];               // clamp(attn*log2e)
    __shared__ float s_bm[LL];
    __shared__ int   csum[64];
    __shared__ int   s_flag, s_maxlvl;

    const int d    = blockIdx.x;
    const int tid  = threadIdx.x;
    const int wid  = tid >> 6;
    const int lane = tid & 63;
    const int my_ni = tid / NG;
    const int my_lg = tid - my_ni * NG;

    const float* atom_d = atom + (size_t)d * NN * LL;
    const int*   pred_d = pred + (size_t)d * NN * PP;
    float*       out_d  = out_all + (size_t)d * NN * LL;

    // ---- W_merge fragments -> registers. Wave w owns nt = min(w,6) ----
    short8 wh[7], wl[7];
    {
        const int r = min(wid, 6)*16 + (lane & 15);
        #pragma unroll
        for (int kt = 0; kt < 7; ++kt) {
            const int k0 = kt*32 + (lane >> 4)*8;
            short8 hh, lo8;
            #pragma unroll
            for (int j = 0; j < 8; ++j) {
                float v = (r < LL && (k0 + j) < 2*LL) ? W_merge[r*2*LL + k0 + j] : 0.f;
                unsigned short a, b;
                split_bf16(v, a, b);
                hh[j] = (short)a; lo8[j] = (short)b;
            }
            wh[kt] = hh; wl[kt] = lo8;
        }
    }

    // ---- init ----
    for (int idx = tid; idx < TMAX * (KP - 2*LL); idx += BT) {
        int rr = idx / (KP - 2*LL), cc = 2*LL + (idx - rr*(KP - 2*LL));
        x_hi[rr][cc] = 0; x_lo[rr][cc] = 0;
    }
    if (tid < LL) {
        s_attn2[tid] = fmaxf(attn_w[tid] * 1.44269504f, 1e-30f);
        s_bm[tid] = b_merge[tid];
        out_lds[0][TMAX][tid] = NEGBIG;    // dummy rows for select-merge
        out_lds[1][TMAX][tid] = NEGBIG;
    }
    if (tid == 0) { s_flag = 0; s_maxlvl = 0; }
    lvl[tid] = 0; lvl[tid + BT] = 0;

    // ---- preds of my 2 nodes -> registers (global, coalesced) ----
    int mypA[PP], mypB[PP];
    {
        const int4* p4 = (const int4*)(pred_d + tid * PP);
        int4 a = p4[0], b = p4[1];
        mypA[0]=a.x; mypA[1]=a.y; mypA[2]=a.z; mypA[3]=a.w;
        mypA[4]=b.x; mypA[5]=b.y; mypA[6]=b.z; mypA[7]=b.w;
        const int4* q4 = (const int4*)(pred_d + (tid + BT) * PP);
        int4 c = q4[0], e = q4[1];
        mypB[0]=c.x; mypB[1]=c.y; mypB[2]=c.z; mypB[3]=c.w;
        mypB[4]=e.x; mypB[5]=e.y; mypB[6]=e.z; mypB[7]=e.w;
    }
    __syncthreads();

    // ---- 1. level relaxation: 2 nodes/thread, double monotone sweep ----
    for (int it = 1; it <= NN; ++it) {
        bool ch = false;
        #pragma unroll
        for (int rep = 0; rep < 2; ++rep) {
            int mxA = -1, mxB = -1;
            #pragma unroll
            for (int q = 0; q < PP; ++q) {
                if (mypA[q] >= 0) mxA = max(mxA, lvl[mypA[q]]);
                if (mypB[q] >= 0) mxB = max(mxB, lvl[mypB[q]]);
            }
            if (mxA + 1 != lvl[tid])      { lvl[tid]      = mxA + 1; ch = true; }
            if (mxB + 1 != lvl[tid + BT]) { lvl[tid + BT] = mxB + 1; ch = true; }
        }
        if (ch) s_flag = it;
        __syncthreads();
        int f = s_flag;
        __syncthreads();
        if (f != it) break;
    }
    atomicMax(&s_maxlvl, max(lvl[tid], lvl[tid + BT]));

    // ---- 2. counting sort by level (order + pos) ----
    cnt[tid] = 0; cnt[tid + BT] = 0;
    __syncthreads();
    atomicAdd(&cnt[lvl[tid]], 1);
    atomicAdd(&cnt[lvl[tid + BT]], 1);
    __syncthreads();
    if (tid < 64) { int s = 0; for (int i = 0; i < 16; ++i) s += cnt[tid*16 + i]; csum[tid] = s; }
    __syncthreads();
    if (tid == 0) { int run = 0; for (int t = 0; t < 64; ++t) { int c = csum[t]; csum[t] = run; run += c; } }
    __syncthreads();
    if (tid < 64) {
        int run = csum[tid];
        for (int i = 0; i < 16; ++i) { int c = cnt[tid*16 + i]; cnt[tid*16 + i] = run; run += c; }
    }
    __syncthreads();
    {
        int pos = atomicAdd(&cnt[lvl[tid]], 1);
        order[pos] = (unsigned short)tid;        pos_lds[tid] = (unsigned short)pos;
        pos = atomicAdd(&cnt[lvl[tid + BT]], 1);
        order[pos] = (unsigned short)(tid + BT); pos_lds[tid + BT] = (unsigned short)pos;
    }
    __syncthreads();

    // ---- 2b. position-space graph: ppos_lds[pos][q] (0xFFFF = none) ----
    {
        unsigned short tA[PP], tB[PP];
        #pragma unroll
        for (int q = 0; q < PP; ++q) {
            tA[q] = (mypA[q] < 0) ? (unsigned short)0xFFFFu : pos_lds[mypA[q]];
            tB[q] = (mypB[q] < 0) ? (unsigned short)0xFFFFu : pos_lds[mypB[q]];
        }
        int pA = pos_lds[tid], pB = pos_lds[tid + BT];
        *(short4v*)&ppos_lds[pA][0] = (short4v){(short)tA[0],(short)tA[1],(short)tA[2],(short)tA[3]};
        *(short4v*)&ppos_lds[pA][4] = (short4v){(short)tA[4],(short)tA[5],(short)tA[6],(short)tA[7]};
        *(short4v*)&ppos_lds[pB][0] = (short4v){(short)tB[0],(short)tB[1],(short)tB[2],(short)tB[3]};
        *(short4v*)&ppos_lds[pB][4] = (short4v){(short)tB[4],(short)tB[5],(short)tB[6],(short)tB[7]};
    }
    __syncthreads();

    const float4 my_aw = *(const float4*)&s_attn2[my_lg * 4];

    // ---- 3. level-0 (root) via W_single; write out_d + out_lds[1] ----
    {
        int nroots = cnt[0];
        for (int task = tid; task < nroots * LL; task += BT) {
            int ni = task / LL, r = task - ni * LL;
            int n = order[ni];
            float acc = b_single[r];
            const float* feat = atom_d + n * LL;
            const float* wr = W_single + r * LL;
            #pragma unroll 8
            for (int l = 0; l < LL; ++l) acc = fmaf(wr[l], feat[l], acc);
            float v = fmaxf(acc, 0.f);
            out_d[n * LL + r] = v;
            if (ni < TMAX) out_lds[1][ni][r] = v;
            if (n == NN - 1) last_buf[d * LL + r] = v;
        }
    }
    __syncthreads();

    const int maxlvl = s_maxlvl;

    // ---- prefetch state for round-1 task (tid) of the NEXT tile ----
    float4  pf_po[PP];               // old preds: global; prev: LDS; fresh/invalid: -3e38
    float4  pf_ft = {0.f,0.f,0.f,0.f};
    short8  pf_pps = {0,0,0,0,0,0,0,0};

    // CT0 = current tile start (pp >= CT0: fresh/invalid -> NEGBIG, resolved
    // in A via the dummy-row fmax merge). PT0/PBUF: previous tile + buffer.
#define PREFETCH(NT0, NTC, CT0, PT0, PBUF) do {                                \
        if (tid < (NTC) * NG) {                                                \
            int n_ = order[(NT0) + my_ni];                                     \
            pf_ft  = *(const float4*)&atom_d[n_ * LL + my_lg * 4];             \
            pf_pps = *(const short8*)&ppos_lds[(NT0) + my_ni][0];              \
            _Pragma("unroll")                                                  \
            for (int q_ = 0; q_ < PP; ++q_) {                                  \
                int pp_ = (unsigned short)pf_pps[q_];                          \
                if (pp_ >= (CT0)) {                                            \
                    pf_po[q_] = (float4){NEGBIG, NEGBIG, NEGBIG, NEGBIG};      \
                } else if (pp_ >= (PT0)) {                                     \
                    pf_po[q_] = *(const float4*)&out_lds[PBUF][pp_ - (PT0)][my_lg * 4]; \
                } else {                                                       \
                    pf_po[q_] = *(const float4*)&out_d[(int)order[pp_] * LL + my_lg * 4]; \
                }                                                              \
            }                                                                  \
        }                                                                      \
    } while (0)

    int pt0 = 0, ptc = cnt[0];
    int wbuf = 0;

    // prologue: first tile of level 1 (all preds level-0 -> out_lds[1])
    if (maxlvl >= 1) {
        int s1 = cnt[0];
        PREFETCH(s1, min(TMAX, cnt[1] - s1), s1, 0, 1);
    }

    // ---- 4. main level loop ----
    for (int L = 1; L <= maxlvl; ++L) {
        const int s = cnt[L - 1], e = cnt[L];
        for (int t0 = s; t0 < e; t0 += TMAX) {
            const int tc = min(TMAX, e - t0);
            const int ntask = tc * NG;
            const int pcopy = ptc * NG;
            const int rbuf = wbuf ^ 1;

            // ---------- phase A ----------
            // deferred global store of PREVIOUS tile: issue FIRST (acks hide
            // under softmax; drained at the full A->B barrier)
            for (int ct = tid; ct < pcopy; ct += BT) {
                int ci = ct / NG, lg2 = ct - ci * NG;
                *(float4*)&out_d[(int)order[pt0 + ci] * LL + lg2 * 4] =
                    *(const float4*)&out_lds[rbuf][ci][lg2 * 4];
            }
            // round 1: LDS + VALU only. Select-merge: exactly one of
            // {out_lds row, pf_po} is NEGBIG; values are post-ReLU >= 0.
            if (tid < ntask) {
                float4 pv[PP];
                #pragma unroll
                for (int q = 0; q < PP; ++q) {
                    unsigned rel = (unsigned)((int)(unsigned short)pf_pps[q] - pt0);
                    int slot = (rel < (unsigned)ptc) ? (int)rel : TMAX;
                    float4 lv = *(const float4*)&out_lds[rbuf][slot][my_lg * 4];
                    pv[q].x = fmaxf(lv.x, pf_po[q].x);
                    pv[q].y = fmaxf(lv.y, pf_po[q].y);
                    pv[q].z = fmaxf(lv.z, pf_po[q].z);
                    pv[q].w = fmaxf(lv.w, pf_po[q].w);
                }
                sm_store3(my_ni, my_lg, my_aw, pv, pf_ft, x_hi, x_lo);
            }
            // rounds 2+ (tc > 19 only)
            for (int task = tid + BT; task < ntask; task += BT) {
                int ni = task / NG, lg = task - ni * NG;
                short8 pps = *(const short8*)&ppos_lds[t0 + ni][0];
                float4 pv[PP];
                #pragma unroll
                for (int q = 0; q < PP; ++q) {
                    int pp = (unsigned short)pps[q];
                    if (pp >= t0) {          // invalid (preds always < t0)
                        pv[q] = (float4){NEGBIG, NEGBIG, NEGBIG, NEGBIG};
                    } else if (pp >= pt0) {  // previous tile -> LDS
                        pv[q] = *(const float4*)&out_lds[rbuf][pp - pt0][lg * 4];
                    } else {                 // old -> global (copied >=1 full barrier ago)
                        pv[q] = *(const float4*)&out_d[(int)order[pp] * LL + lg * 4];
                    }
                }
                int n = order[t0 + ni];
                float4 ft = *(const float4*)&atom_d[n * LL + lg * 4];
                float4 aw4 = *(const float4*)&s_attn2[lg * 4];
                sm_store3(ni, lg, aw4, pv, ft, x_hi, x_lo);
            }
            __syncthreads();   // FULL: x visible; copy stores drained

            // ---------- phase B ----------
            // next tile's prefetch first (loads fly under MFMA and across
            // the raw barrier into next A)
            {
                int nt0 = 0, ntc = 0;
                if (t0 + TMAX < e)        { nt0 = t0 + TMAX; ntc = min(TMAX, e - nt0); }
                else if (L + 1 <= maxlvl) { nt0 = e;         ntc = min(TMAX, cnt[L + 1] - e); }
                PREFETCH(nt0, ntc, t0, pt0, rbuf);
            }

            if (wid < 7) {
                const int mts = (tc + 15) >> 4;
                const int kg = (lane >> 4) * 8;
                const int r0 = wid*16 + (lane & 15);
                for (int mt = 0; mt < mts; ++mt) {
                    const int row_a = mt*16 + (lane & 15);
                    f32x4 a0 = {0.f,0.f,0.f,0.f}, b0 = {0.f,0.f,0.f,0.f}, c0 = {0.f,0.f,0.f,0.f};
                    #pragma unroll
                    for (int kt = 0; kt < 7; ++kt) {
                        const int k0 = kt*32 + kg;
                        short8 ah = *(const short8*)&x_hi[row_a][k0];
                        short8 al = *(const short8*)&x_lo[row_a][k0];
                        a0 = MFMA(ah, wh[kt], a0);
                        b0 = MFMA(ah, wl[kt], b0);
                        c0 = MFMA(al, wh[kt], c0);
                    }
                    f32x4 acc = a0 + b0 + c0;
                    if (r0 < LL) {
                        #pragma unroll
                        for (int j = 0; j < 4; ++j) {
                            int ni = mt*16 + (lane >> 4)*4 + j;
                            if (ni < tc) {
                                float v = fmaxf(acc[j] + s_bm[r0], 0.f);
                                out_lds[wbuf][ni][r0] = v;      // LDS only
                                int n = order[t0 + ni];
                                if (n == NN - 1) last_buf[d*LL + r0] = v;
                            }
                        }
                    }
                }
            }
            BAR_RAW();   // lgkm-only: out_lds visible; prefetch stays in flight
            pt0 = t0; ptc = tc; wbuf ^= 1;
        }
    }
#undef PREFETCH
}

// Cross-DAG softmax pool: 104 features x 4 DAG-groups of 64, LDS combine.
__global__ __launch_bounds__(512) void pool_kernel(
    const float* __restrict__ last_buf,  // [DN][LL]
    const float* __restrict__ dag_w,     // [LL]
    float* __restrict__ pooled)          // ws: [LL]
{
    __shared__ float sm[4][LL], sden[4][LL], snum[4][LL];
    const int t = threadIdx.x;

    if (t < LL * 4) {
        const int l = t >> 2, g = t & 3;
        const float dw = dag_w[l];
        const float* p = last_buf + (size_t)g * 64 * LL + l;
        float m = -1e30f;
        #pragma unroll 8
        for (int i = 0; i < 64; ++i) m = fmaxf(m, dw * p[i * LL]);
        float den = 0.f, num = 0.f;
        #pragma unroll 8
        for (int i = 0; i < 64; ++i) {
            float v = p[i * LL];
            float e = __expf(fmaf(dw, v, -m));
            den += e;
            num = fmaf(e, v, num);
        }
        sm[g][l] = m; sden[g][l] = den; snum[g][l] = num;
    }
    __syncthreads();
    if (t < LL) {
        float M = fmaxf(fmaxf(sm[0][t], sm[1][t]), fmaxf(sm[2][t], sm[3][t]));
        float den = 0.f, num = 0.f;
        #pragma unroll
        for (int g = 0; g < 4; ++g) {
            float s = __expf(sm[g][t] - M);
            den = fmaf(sden[g][t], s, den);
            num = fmaf(snum[g][t], s, num);
        }
        pooled[t] = __fdividef(num, den);
    }
}

// Final classifier: 8 blocks x 64 threads, one class per thread.
__global__ __launch_bounds__(64) void classifier_kernel(
    const float* __restrict__ pooled,    // ws: [LL]
    const float* __restrict__ W_final,   // [CLS][LL]
    const float* __restrict__ b_final,   // [CLS]
    float* __restrict__ out)             // [CLS]
{
    __shared__ float sp[LL];
    const int t = threadIdx.x;
    for (int i = t; i < LL; i += 64) sp[i] = pooled[i];
    __syncthreads();
    const int c = blockIdx.x * 64 + t;
    if (c < CLS) {
        float acc = b_final[c];
        const float* wr = W_final + c * LL;
        #pragma unroll 8
        for (int l = 0; l < LL; ++l) acc = fmaf(wr[l], sp[l], acc);
        out[c] = acc;
    }
}

extern "C" void kernel_launch(void* const* d_in, const int* in_sizes, int n_in,
                              void* d_out, int out_size, void* d_ws, size_t ws_size,
                              hipStream_t stream) {
    const float* atom     = (const float*)d_in[0];
    const int*   pred     = (const int*)  d_in[1];
    const float* W_single = (const float*)d_in[2];
    const float* b_single = (const float*)d_in[3];
    const float* W_merge  = (const float*)d_in[4];
    const float* b_merge  = (const float*)d_in[5];
    const float* attn_w   = (const float*)d_in[6];
    const float* dag_w    = (const float*)d_in[7];
    const float* W_final  = (const float*)d_in[8];
    const float* b_final  = (const float*)d_in[9];
    float* out = (float*)d_out;

    float* out_all  = (float*)d_ws;                       // [DN][NN][LL]
    float* last_buf = out_all + (size_t)DN * NN * LL;     // [DN][LL]
    float* pooled   = last_buf + (size_t)DN * LL;         // [LL]

    dag_level_kernel<<<DN, BT, 0, stream>>>(atom, pred, W_single, b_single,
                                            W_merge, b_merge, attn_w,
                                            out_all, last_buf);
    pool_kernel<<<1, 512, 0, stream>>>(last_buf, dag_w, pooled);
    classifier_kernel<<<(CLS + 63) / 64, 64, 0, stream>>>(pooled, W_final, b_final, out);
}

// Round 18
// 319.696 us; speedup vs baseline: 1.2540x; 1.0040x over previous
//
#include <hip/hip_runtime.h>

#define DN  256   // DAGs
#define NN  1024  // nodes per DAG
#define PP  8     // max predecessors
#define LL  104   // feature dim
#define CLS 500   // classes
#define BT  512   // threads per block (8 waves)
#define TMAX 64   // node tile per level pass
#define KP  232   // padded K stride in bf16 elems
#define NG  26    // float4 feature groups (104/4)
#define OLP 108   // out_lds row pad (432B rows)
#define NEGBIG -3.0e38f

typedef __attribute__((ext_vector_type(8))) short short8;
typedef __attribute__((ext_vector_type(4))) short short4v;
typedef __attribute__((ext_vector_type(4))) float f32x4;

#define MFMA(a, b, c) __builtin_amdgcn_mfma_f32_16x16x32_bf16((a), (b), (c), 0, 0, 0)

// Raw barrier: LDS-visibility only; vmcnt NOT drained.
#define BAR_RAW() do {                                              \
    __builtin_amdgcn_sched_barrier(0);                              \
    asm volatile("s_waitcnt lgkmcnt(0)" ::: "memory");              \
    __builtin_amdgcn_s_barrier();                                   \
    __builtin_amdgcn_sched_barrier(0);                              \
} while (0)

__device__ __forceinline__ void split_bf16(float x, unsigned short& h, unsigned short& l) {
    unsigned u = __float_as_uint(x);
    h = (unsigned short)(u >> 16);
    float hf = __uint_as_float(u & 0xFFFF0000u);
    l = (unsigned short)(__float_as_uint(x - hf) >> 16);
}

__device__ __forceinline__ void split4(float4 v, short4v& h4, short4v& l4) {
    unsigned short h0,h1,h2,h3,l0,l1,l2,l3;
    split_bf16(v.x,h0,l0); split_bf16(v.y,h1,l1);
    split_bf16(v.z,h2,l2); split_bf16(v.w,h3,l3);
    h4 = (short4v){(short)h0,(short)h1,(short)h2,(short)h3};
    l4 = (short4v){(short)l0,(short)l1,(short)l2,(short)l3};
}

// softmax over preds + split-bf16 + x store; ft arrives PRE-SPLIT.
// Invalid/skipped preds carry pv = -3e38 so raw exp2(aw*pv) == 0 exactly.
__device__ __forceinline__ void sm_store3(int ni, int lg, float4 aw4,
    const float4 pv[PP], short4v fth, short4v ftl,
    unsigned short (*xh)[KP], unsigned short (*xl)[KP])
{
    float awv[4] = {aw4.x, aw4.y, aw4.z, aw4.w};
    unsigned short oh[4], ol[4];
    #pragma unroll
    for (int f = 0; f < 4; ++f) {
        float den = 0.f, num = 0.f;
        #pragma unroll
        for (int q = 0; q < PP; ++q) {
            float pvq = ((const float*)&pv[q])[f];
            float e2 = __builtin_amdgcn_exp2f(awv[f] * pvq);   // raw v_exp_f32
            den += e2;
            num = fmaf(e2, pvq, num);
        }
        float agg = __fdividef(num, den);
        split_bf16(agg, oh[f], ol[f]);
    }
    *(short4v*)&xh[ni][lg*4] = (short4v){(short)oh[0],(short)oh[1],(short)oh[2],(short)oh[3]};
    *(short4v*)&xl[ni][lg*4] = (short4v){(short)ol[0],(short)ol[1],(short)ol[2],(short)ol[3]};
    *(short4v*)&xh[ni][LL + lg*4] = fth;
    *(short4v*)&xl[ni][LL + lg*4] = ftl;
}

// One block per DAG, 8 waves. Level-scheduled split-bf16 MFMA GEMM per level.
// Double-buffered out_lds (+ NEGBIG dummy row); prev-tile preds from LDS; old
// preds prefetched in phase B and kept in flight across a RAW (lgkm-only)
// B->A barrier. Phase B stores results to global DIRECTLY from registers
// (acks drain two barriers later; no copy loop in phase A).
__global__ __launch_bounds__(BT, 2) void dag_level_kernel(
    const float* __restrict__ atom,      // [DN][NN][LL]
    const int*   __restrict__ pred,      // [DN][NN][PP]
    const float* __restrict__ W_single,  // [LL][LL]
    const float* __restrict__ b_single,  // [LL]
    const float* __restrict__ W_merge,   // [LL][2*LL]
    const float* __restrict__ b_merge,   // [LL]
    const float* __restrict__ attn_w,    // [LL]
    float* __restrict__ out_all,         // ws: [DN][NN][LL]
    float* __restrict__ last_buf)        // ws: [DN][LL]
{
    __shared__ __align__(16) unsigned short x_hi[TMAX][KP];   // 29 KB
    __shared__ __align__(16) unsigned short x_lo[TMAX][KP];   // 29 KB
    __shared__ __align__(16) unsigned short ppos_lds[NN][PP]; // 16 KB pred positions
    __shared__ __align__(16) float out_lds[2][TMAX+1][OLP];   // 56 KB dbuf + dummy row
    __shared__ int   lvl[NN];                                 // 4 KB
    __shared__ int   cnt[NN];                                 // 4 KB
    __shared__ unsigned short order[NN];                      // 2 KB pos -> node
    __shared__ unsigned short pos_lds[NN];                    // 2 KB node -> pos
    __shared__ __align__(16) float s_attn2[LL];               // clamp(attn*log2e)
    __shared__ float s_bm[LL];
    __shared__ int   csum[64];
    __shared__ int   s_flag, s_maxlvl;

    const int d    = blockIdx.x;
    const int tid  = threadIdx.x;
    const int wid  = tid >> 6;
    const int lane = tid & 63;
    const int my_ni = tid / NG;
    const int my_lg = tid - my_ni * NG;

    const float* atom_d = atom + (size_t)d * NN * LL;
    const int*   pred_d = pred + (size_t)d * NN * PP;
    float*       out_d  = out_all + (size_t)d * NN * LL;

    // ---- W_merge fragments -> registers. Wave w owns nt = min(w,6) ----
    short8 wh[7], wl[7];
    {
        const int r = min(wid, 6)*16 + (lane & 15);
        #pragma unroll
        for (int kt = 0; kt < 7; ++kt) {
            const int k0 = kt*32 + (lane >> 4)*8;
            short8 hh, lo8;
            #pragma unroll
            for (int j = 0; j < 8; ++j) {
                float v = (r < LL && (k0 + j) < 2*LL) ? W_merge[r*2*LL + k0 + j] : 0.f;
                unsigned short a, b;
                split_bf16(v, a, b);
                hh[j] = (short)a; lo8[j] = (short)b;
            }
            wh[kt] = hh; wl[kt] = lo8;
        }
    }

    // ---- init ----
    for (int idx = tid; idx < TMAX * (KP - 2*LL); idx += BT) {
        int rr = idx / (KP - 2*LL), cc = 2*LL + (idx - rr*(KP - 2*LL));
        x_hi[rr][cc] = 0; x_lo[rr][cc] = 0;
    }
    if (tid < LL) {
        s_attn2[tid] = fmaxf(attn_w[tid] * 1.44269504f, 1e-30f);
        s_bm[tid] = b_merge[tid];
        out_lds[0][TMAX][tid] = NEGBIG;    // dummy rows for select-merge
        out_lds[1][TMAX][tid] = NEGBIG;
    }
    if (tid == 0) { s_flag = 0; s_maxlvl = 0; }
    lvl[tid] = 0; lvl[tid + BT] = 0;

    // ---- preds of my 2 nodes -> registers (global, coalesced) ----
    int mypA[PP], mypB[PP];
    {
        const int4* p4 = (const int4*)(pred_d + tid * PP);
        int4 a = p4[0], b = p4[1];
        mypA[0]=a.x; mypA[1]=a.y; mypA[2]=a.z; mypA[3]=a.w;
        mypA[4]=b.x; mypA[5]=b.y; mypA[6]=b.z; mypA[7]=b.w;
        const int4* q4 = (const int4*)(pred_d + (tid + BT) * PP);
        int4 c = q4[0], e = q4[1];
        mypB[0]=c.x; mypB[1]=c.y; mypB[2]=c.z; mypB[3]=c.w;
        mypB[4]=e.x; mypB[5]=e.y; mypB[6]=e.z; mypB[7]=e.w;
    }
    __syncthreads();

    // ---- 1. level relaxation: 2 nodes/thread, double monotone sweep ----
    for (int it = 1; it <= NN; ++it) {
        bool ch = false;
        #pragma unroll
        for (int rep = 0; rep < 2; ++rep) {
            int mxA = -1, mxB = -1;
            #pragma unroll
            for (int q = 0; q < PP; ++q) {
                if (mypA[q] >= 0) mxA = max(mxA, lvl[mypA[q]]);
                if (mypB[q] >= 0) mxB = max(mxB, lvl[mypB[q]]);
            }
            if (mxA + 1 != lvl[tid])      { lvl[tid]      = mxA + 1; ch = true; }
            if (mxB + 1 != lvl[tid + BT]) { lvl[tid + BT] = mxB + 1; ch = true; }
        }
        if (ch) s_flag = it;
        __syncthreads();
        int f = s_flag;
        __syncthreads();
        if (f != it) break;
    }
    atomicMax(&s_maxlvl, max(lvl[tid], lvl[tid + BT]));

    // ---- 2. counting sort by level (order + pos) ----
    cnt[tid] = 0; cnt[tid + BT] = 0;
    __syncthreads();
    atomicAdd(&cnt[lvl[tid]], 1);
    atomicAdd(&cnt[lvl[tid + BT]], 1);
    __syncthreads();
    if (tid < 64) { int s = 0; for (int i = 0; i < 16; ++i) s += cnt[tid*16 + i]; csum[tid] = s; }
    __syncthreads();
    if (tid == 0) { int run = 0; for (int t = 0; t < 64; ++t) { int c = csum[t]; csum[t] = run; run += c; } }
    __syncthreads();
    if (tid < 64) {
        int run = csum[tid];
        for (int i = 0; i < 16; ++i) { int c = cnt[tid*16 + i]; cnt[tid*16 + i] = run; run += c; }
    }
    __syncthreads();
    {
        int pos = atomicAdd(&cnt[lvl[tid]], 1);
        order[pos] = (unsigned short)tid;        pos_lds[tid] = (unsigned short)pos;
        pos = atomicAdd(&cnt[lvl[tid + BT]], 1);
        order[pos] = (unsigned short)(tid + BT); pos_lds[tid + BT] = (unsigned short)pos;
    }
    __syncthreads();

    // ---- 2b. position-space graph: ppos_lds[pos][q] (0xFFFF = none) ----
    {
        unsigned short tA[PP], tB[PP];
        #pragma unroll
        for (int q = 0; q < PP; ++q) {
            tA[q] = (mypA[q] < 0) ? (unsigned short)0xFFFFu : pos_lds[mypA[q]];
            tB[q] = (mypB[q] < 0) ? (unsigned short)0xFFFFu : pos_lds[mypB[q]];
        }
        int pA = pos_lds[tid], pB = pos_lds[tid + BT];
        *(short4v*)&ppos_lds[pA][0] = (short4v){(short)tA[0],(short)tA[1],(short)tA[2],(short)tA[3]};
        *(short4v*)&ppos_lds[pA][4] = (short4v){(short)tA[4],(short)tA[5],(short)tA[6],(short)tA[7]};
        *(short4v*)&ppos_lds[pB][0] = (short4v){(short)tB[0],(short)tB[1],(short)tB[2],(short)tB[3]};
        *(short4v*)&ppos_lds[pB][4] = (short4v){(short)tB[4],(short)tB[5],(short)tB[6],(short)tB[7]};
    }
    __syncthreads();

    const float4 my_aw = *(const float4*)&s_attn2[my_lg * 4];

    // ---- 3. level-0 (root) via W_single; write out_d + out_lds[1] ----
    {
        int nroots = cnt[0];
        for (int task = tid; task < nroots * LL; task += BT) {
            int ni = task / LL, r = task - ni * LL;
            int n = order[ni];
            float acc = b_single[r];
            const float* feat = atom_d + n * LL;
            const float* wr = W_single + r * LL;
            #pragma unroll 8
            for (int l = 0; l < LL; ++l) acc = fmaf(wr[l], feat[l], acc);
            float v = fmaxf(acc, 0.f);
            out_d[n * LL + r] = v;
            if (ni < TMAX) out_lds[1][ni][r] = v;
            if (n == NN - 1) last_buf[d * LL + r] = v;
        }
    }
    __syncthreads();

    const int maxlvl = s_maxlvl;

    // ---- prefetch state for round-1 task (tid) of the NEXT tile ----
    float4  pf_po[PP];               // old preds: global; prev: LDS; fresh/invalid: -3e38
    short4v pf_fth = {0,0,0,0}, pf_ftl = {0,0,0,0};   // pre-split feat
    short8  pf_pps = {0,0,0,0,0,0,0,0};

    // CT0 = current tile start (pp >= CT0: fresh/invalid -> NEGBIG, resolved
    // in A via the dummy-row fmax merge). PT0/PBUF: previous tile + buffer.
#define PREFETCH(NT0, NTC, CT0, PT0, PBUF) do {                                \
        if (tid < (NTC) * NG) {                                                \
            int n_ = order[(NT0) + my_ni];                                     \
            float4 ft_ = *(const float4*)&atom_d[n_ * LL + my_lg * 4];         \
            split4(ft_, pf_fth, pf_ftl);                                       \
            pf_pps = *(const short8*)&ppos_lds[(NT0) + my_ni][0];              \
            _Pragma("unroll")                                                  \
            for (int q_ = 0; q_ < PP; ++q_) {                                  \
                int pp_ = (unsigned short)pf_pps[q_];                          \
                if (pp_ >= (CT0)) {                                            \
                    pf_po[q_] = (float4){NEGBIG, NEGBIG, NEGBIG, NEGBIG};      \
                } else if (pp_ >= (PT0)) {                                     \
                    pf_po[q_] = *(const float4*)&out_lds[PBUF][pp_ - (PT0)][my_lg * 4]; \
                } else {                                                       \
                    pf_po[q_] = *(const float4*)&out_d[(int)order[pp_] * LL + my_lg * 4]; \
                }                                                              \
            }                                                                  \
        }                                                                      \
    } while (0)

    int pt0 = 0, ptc = cnt[0];
    int wbuf = 0;

    // prologue: first tile of level 1 (all preds level-0 -> out_lds[1])
    if (maxlvl >= 1) {
        int s1 = cnt[0];
        PREFETCH(s1, min(TMAX, cnt[1] - s1), s1, 0, 1);
    }

    // ---- 4. main level loop ----
    for (int L = 1; L <= maxlvl; ++L) {
        const int s = cnt[L - 1], e = cnt[L];
        for (int t0 = s; t0 < e; t0 += TMAX) {
            const int tc = min(TMAX, e - t0);
            const int ntask = tc * NG;
            const int rbuf = wbuf ^ 1;

            // ---------- phase A ----------
            // round 1: LDS + VALU only. Select-merge: exactly one of
            // {out_lds row, pf_po} is NEGBIG; values are post-ReLU >= 0.
            if (tid < ntask) {
                float4 pv[PP];
                #pragma unroll
                for (int q = 0; q < PP; ++q) {
                    unsigned rel = (unsigned)((int)(unsigned short)pf_pps[q] - pt0);
                    int slot = (rel < (unsigned)ptc) ? (int)rel : TMAX;
                    float4 lv = *(const float4*)&out_lds[rbuf][slot][my_lg * 4];
                    pv[q].x = fmaxf(lv.x, pf_po[q].x);
                    pv[q].y = fmaxf(lv.y, pf_po[q].y);
                    pv[q].z = fmaxf(lv.z, pf_po[q].z);
                    pv[q].w = fmaxf(lv.w, pf_po[q].w);
                }
                sm_store3(my_ni, my_lg, my_aw, pv, pf_fth, pf_ftl, x_hi, x_lo);
            }
            // rounds 2+ (tc > 19 only)
            for (int task = tid + BT; task < ntask; task += BT) {
                int ni = task / NG, lg = task - ni * NG;
                short8 pps = *(const short8*)&ppos_lds[t0 + ni][0];
                float4 pv[PP];
                #pragma unroll
                for (int q = 0; q < PP; ++q) {
                    int pp = (unsigned short)pps[q];
                    if (pp >= t0) {          // invalid (preds always < t0)
                        pv[q] = (float4){NEGBIG, NEGBIG, NEGBIG, NEGBIG};
                    } else if (pp >= pt0) {  // previous tile -> LDS
                        pv[q] = *(const float4*)&out_lds[rbuf][pp - pt0][lg * 4];
                    } else {                 // old -> global (stored >=2 full barriers ago)
                        pv[q] = *(const float4*)&out_d[(int)order[pp] * LL + lg * 4];
                    }
                }
                int n = order[t0 + ni];
                float4 ft = *(const float4*)&atom_d[n * LL + lg * 4];
                short4v fth, ftl;
                split4(ft, fth, ftl);
                float4 aw4 = *(const float4*)&s_attn2[lg * 4];
                sm_store3(ni, lg, aw4, pv, fth, ftl, x_hi, x_lo);
            }
            __syncthreads();   // FULL: x visible; prior-tile B-stores drained

            // ---------- phase B ----------
            // next tile's prefetch first (loads fly under MFMA and across
            // the raw barrier into next A)
            {
                int nt0 = 0, ntc = 0;
                if (t0 + TMAX < e)        { nt0 = t0 + TMAX; ntc = min(TMAX, e - nt0); }
                else if (L + 1 <= maxlvl) { nt0 = e;         ntc = min(TMAX, cnt[L + 1] - e); }
                PREFETCH(nt0, ntc, t0, pt0, rbuf);
            }

            if (wid < 7) {
                const int mts = (tc + 15) >> 4;
                const int kg = (lane >> 4) * 8;
                const int r0 = wid*16 + (lane & 15);
                for (int mt = 0; mt < mts; ++mt) {
                    const int row_a = mt*16 + (lane & 15);
                    f32x4 a0 = {0.f,0.f,0.f,0.f}, b0 = {0.f,0.f,0.f,0.f}, c0 = {0.f,0.f,0.f,0.f};
                    #pragma unroll
                    for (int kt = 0; kt < 7; ++kt) {
                        const int k0 = kt*32 + kg;
                        short8 ah = *(const short8*)&x_hi[row_a][k0];
                        short8 al = *(const short8*)&x_lo[row_a][k0];
                        a0 = MFMA(ah, wh[kt], a0);
                        b0 = MFMA(ah, wl[kt], b0);
                        c0 = MFMA(al, wh[kt], c0);
                    }
                    f32x4 acc = a0 + b0 + c0;
                    if (r0 < LL) {
                        #pragma unroll
                        for (int j = 0; j < 4; ++j) {
                            int ni = mt*16 + (lane >> 4)*4 + j;
                            if (ni < tc) {
                                float v = fmaxf(acc[j] + s_bm[r0], 0.f);
                                out_lds[wbuf][ni][r0] = v;       // LDS mirror
                                int n = order[t0 + ni];
                                out_d[n*LL + r0] = v;            // direct global store;
                                                                 // ack drains 2 barriers later
                                if (n == NN - 1) last_buf[d*LL + r0] = v;
                            }
                        }
                    }
                }
            }
            BAR_RAW();   // lgkm-only: out_lds visible; loads/stores stay in flight
            pt0 = t0; ptc = tc; wbuf ^= 1;
        }
    }
#undef PREFETCH
}

// Cross-DAG softmax pool: 104 features x 4 DAG-groups of 64, LDS combine.
__global__ __launch_bounds__(512) void pool_kernel(
    const float* __restrict__ last_buf,  // [DN][LL]
    const float* __restrict__ dag_w,     // [LL]
    float* __restrict__ pooled)          // ws: [LL]
{
    __shared__ float sm[4][LL], sden[4][LL], snum[4][LL];
    const int t = threadIdx.x;

    if (t < LL * 4) {
        const int l = t >> 2, g = t & 3;
        const float dw = dag_w[l];
        const float* p = last_buf + (size_t)g * 64 * LL + l;
        float m = -1e30f;
        #pragma unroll 8
        for (int i = 0; i < 64; ++i) m = fmaxf(m, dw * p[i * LL]);
        float den = 0.f, num = 0.f;
        #pragma unroll 8
        for (int i = 0; i < 64; ++i) {
            float v = p[i * LL];
            float e = __expf(fmaf(dw, v, -m));
            den += e;
            num = fmaf(e, v, num);
        }
        sm[g][l] = m; sden[g][l] = den; snum[g][l] = num;
    }
    __syncthreads();
    if (t < LL) {
        float M = fmaxf(fmaxf(sm[0][t], sm[1][t]), fmaxf(sm[2][t], sm[3][t]));
        float den = 0.f, num = 0.f;
        #pragma unroll
        for (int g = 0; g < 4; ++g) {
            float s = __expf(sm[g][t] - M);
            den = fmaf(sden[g][t], s, den);
            num = fmaf(snum[g][t], s, num);
        }
        pooled[t] = __fdividef(num, den);
    }
}

// Final classifier: 8 blocks x 64 threads, one class per thread.
__global__ __launch_bounds__(64) void classifier_kernel(
    const float* __restrict__ pooled,    // ws: [LL]
    const float* __restrict__ W_final,   // [CLS][LL]
    const float* __restrict__ b_final,   // [CLS]
    float* __restrict__ out)             // [CLS]
{
    __shared__ float sp[LL];
    const int t = threadIdx.x;
    for (int i = t; i < LL; i += 64) sp[i] = pooled[i];
    __syncthreads();
    const int c = blockIdx.x * 64 + t;
    if (c < CLS) {
        float acc = b_final[c];
        const float* wr = W_final + c * LL;
        #pragma unroll 8
        for (int l = 0; l < LL; ++l) acc = fmaf(wr[l], sp[l], acc);
        out[c] = acc;
    }
}

extern "C" void kernel_launch(void* const* d_in, const int* in_sizes, int n_in,
                              void* d_out, int out_size, void* d_ws, size_t ws_size,
                              hipStream_t stream) {
    const float* atom     = (const float*)d_in[0];
    const int*   pred     = (const int*)  d_in[1];
    const float* W_single = (const float*)d_in[2];
    const float* b_single = (const float*)d_in[3];
    const float* W_merge  = (const float*)d_in[4];
    const float* b_merge  = (const float*)d_in[5];
    const float* attn_w   = (const float*)d_in[6];
    const float* dag_w    = (const float*)d_in[7];
    const float* W_final  = (const float*)d_in[8];
    const float* b_final  = (const float*)d_in[9];
    float* out = (float*)d_out;

    float* out_all  = (float*)d_ws;                       // [DN][NN][LL]
    float* last_buf = out_all + (size_t)DN * NN * LL;     // [DN][LL]
    float* pooled   = last_buf + (size_t)DN * LL;         // [LL]

    dag_level_kernel<<<DN, BT, 0, stream>>>(atom, pred, W_single, b_single,
                                            W_merge, b_merge, attn_w,
                                            out_all, last_buf);
    pool_kernel<<<1, 512, 0, stream>>>(last_buf, dag_w, pooled);
    classifier_kernel<<<(CLS + 63) / 64, 64, 0, stream>>>(pooled, W_final, b_final, out);
}